// Round 1
// baseline (308.979 us; speedup 1.0000x reference)
//
#include <hip/hip_runtime.h>
#include <stdint.h>

typedef __attribute__((ext_vector_type(8))) short bf16x8;
typedef __attribute__((ext_vector_type(4))) float f32x4;

#define MFMA16(a,b,c) __builtin_amdgcn_mfma_f32_16x16x32_bf16(a,b,c,0,0,0)

typedef const __attribute__((address_space(1))) void GV;
typedef __attribute__((address_space(3))) void LV;

static __device__ __forceinline__ void gload16(const void* g, void* l) {
  __builtin_amdgcn_global_load_lds((GV*)g, (LV*)l, 16, 0, 0);
}

static __device__ __forceinline__ unsigned short f2bf(float f) {
  union { float f; unsigned u; } x; x.f = f;
  unsigned r = x.u + 0x7FFFu + ((x.u >> 16) & 1u);
  return (unsigned short)(r >> 16);
}

// ---------------- pack kernels ----------------
__global__ __launch_bounds__(256) void pack_x_kernel(
    const float* __restrict__ x, unsigned short* __restrict__ xb) {
  int i = blockIdx.x * 256 + threadIdx.x;           // handles 4 elements
  float4 v = ((const float4*)x)[i];
  unsigned a0 = f2bf(v.x), a1 = f2bf(v.y), a2 = f2bf(v.z), a3 = f2bf(v.w);
  uint2 pk; pk.x = a0 | (a1 << 16); pk.y = a2 | (a3 << 16);
  ((uint2*)xb)[i] = pk;
}

__global__ __launch_bounds__(256) void pack_w_kernel(
    const float* __restrict__ Wq, const float* __restrict__ Wkv,
    const float* __restrict__ Wp, const float* __restrict__ Wsr,
    unsigned short* __restrict__ wqt, unsigned short* __restrict__ wkvt,
    unsigned short* __restrict__ wpt, unsigned short* __restrict__ wsrt) {
  int idx = blockIdx.x * 256 + threadIdx.x;         // total 5,242,880
  if (idx < 262144) {
    int n = idx >> 9, k = idx & 511;
    wqt[idx] = f2bf(Wq[k * 512 + n]);
  } else if (idx < 786432) {
    int j = idx - 262144; int n = j >> 9, k = j & 511;
    wkvt[j] = f2bf(Wkv[k * 1024 + n]);
  } else if (idx < 1048576) {
    int j = idx - 786432; int n = j >> 9, k = j & 511;
    wpt[j] = f2bf(Wp[k * 512 + n]);
  } else {
    int j = idx - 1048576;
    int oc = j >> 13, rem = j & 8191;
    int r12 = rem >> 9, ic = rem & 511;
    wsrt[j] = f2bf(Wsr[oc * 8192 + ic * 16 + r12]);
  }
}

// ---------------- GEMM: C = A(bf16,[M][K or gathered]) * Bt(bf16,[N][K])^T + bias ----------------
// MODE 0: fp32 row-major out; MODE 1: bf16 row-major out; MODE 2: k/vT scatter (KV proj)
template<int WM, int WN, int MREP, int NREP, int MODE, bool CONV>
__global__ __launch_bounds__(256) void gemm_bf16(
    const unsigned short* __restrict__ A, const unsigned short* __restrict__ Bt,
    const float* __restrict__ bias, void* __restrict__ outp,
    unsigned short* __restrict__ out_k, unsigned short* __restrict__ out_v,
    int M, int N, int K, int lda) {
  constexpr int BM = WM * MREP * 16;
  constexpr int BN = WN * NREP * 16;
  constexpr int BK = 64;
  __shared__ unsigned short lds_a[BM * BK];
  __shared__ unsigned short lds_b[BN * BK];
  const int tid = threadIdx.x;
  const int lane = tid & 63, w = tid >> 6;
  const int wr = w / WN, wc = w % WN;
  const int l15 = lane & 15, lhi = lane >> 4;
  const int m0 = blockIdx.x * BM;
  const int n0 = blockIdx.y * BN;

  f32x4 acc[MREP][NREP] = {};
  constexpr int AR = (BM * BK * 2) / 4096;
  constexpr int BR = (BN * BK * 2) / 4096;

  for (int k0 = 0; k0 < K; k0 += BK) {
    #pragma unroll
    for (int r = 0; r < AR; ++r) {
      int o = r * 4096 + tid * 16;          // byte offset in lds_a
      int row = o >> 7;                     // 128 B per row (64 bf16)
      int kc = (o & 127) >> 1;
      const unsigned short* src;
      if constexpr (CONV) {
        int m = m0 + row;
        int bb = m >> 8, pix = m & 255;
        int oh = pix >> 4, ow = pix & 15;
        int r12 = k0 >> 9;
        int icc = (k0 & 511) + kc;
        int r1 = r12 >> 2, r2 = r12 & 3;
        int nn = (oh * 4 + r1) * 64 + ow * 4 + r2;
        src = A + ((size_t)(bb * 4096 + nn)) * 512 + icc;
      } else {
        src = A + (size_t)(m0 + row) * lda + k0 + kc;
      }
      gload16(src, (char*)lds_a + r * 4096 + w * 1024);
    }
    #pragma unroll
    for (int r = 0; r < BR; ++r) {
      int o = r * 4096 + tid * 16;
      int row = o >> 7;
      int kc = (o & 127) >> 1;
      const unsigned short* src = Bt + (size_t)(n0 + row) * K + k0 + kc;
      gload16(src, (char*)lds_b + r * 4096 + w * 1024);
    }
    __syncthreads();
    #pragma unroll
    for (int kk = 0; kk < BK; kk += 32) {
      bf16x8 af[MREP], bfr[NREP];
      #pragma unroll
      for (int m = 0; m < MREP; ++m)
        af[m] = *(const bf16x8*)&lds_a[(wr * MREP * 16 + m * 16 + l15) * BK + kk + lhi * 8];
      #pragma unroll
      for (int n = 0; n < NREP; ++n)
        bfr[n] = *(const bf16x8*)&lds_b[(wc * NREP * 16 + n * 16 + l15) * BK + kk + lhi * 8];
      #pragma unroll
      for (int m = 0; m < MREP; ++m)
        #pragma unroll
        for (int n = 0; n < NREP; ++n)
          acc[m][n] = MFMA16(af[m], bfr[n], acc[m][n]);
    }
    __syncthreads();
  }

  #pragma unroll
  for (int m = 0; m < MREP; ++m) {
    #pragma unroll
    for (int n = 0; n < NREP; ++n) {
      #pragma unroll
      for (int r = 0; r < 4; ++r) {
        int gm = m0 + wr * MREP * 16 + m * 16 + lhi * 4 + r;
        int gn = n0 + wc * NREP * 16 + n * 16 + l15;
        float v = acc[m][n][r] + bias[gn];
        if constexpr (MODE == 0) {
          ((float*)outp)[(size_t)gm * N + gn] = v;
        } else if constexpr (MODE == 1) {
          ((unsigned short*)outp)[(size_t)gm * N + gn] = f2bf(v);
        } else {
          unsigned short bv = f2bf(v);
          int bb = gm >> 8, nr = gm & 255;
          if (gn < 512) {
            int hh = gn >> 6, d = gn & 63;
            out_k[(((size_t)bb * 8 + hh) * 256 + nr) * 64 + d] = bv;
          } else {
            int c = gn - 512;
            int hh = c >> 6, d = c & 63;
            out_v[(((size_t)bb * 8 + hh) * 64 + d) * 256 + nr] = bv;
          }
        }
      }
    }
  }
}

// ---------------- LayerNorm over C=512, one wave per row ----------------
__global__ __launch_bounds__(64) void ln_kernel(
    const float* __restrict__ xr, const float* __restrict__ gamma,
    const float* __restrict__ beta, unsigned short* __restrict__ xln) {
  const int row = blockIdx.x, lane = threadIdx.x;
  const float* p = xr + (size_t)row * 512 + lane * 8;
  float4 v0 = *(const float4*)p;
  float4 v1 = *(const float4*)(p + 4);
  float vv[8] = {v0.x, v0.y, v0.z, v0.w, v1.x, v1.y, v1.z, v1.w};
  float s = 0.f, s2 = 0.f;
  #pragma unroll
  for (int j = 0; j < 8; ++j) { s += vv[j]; s2 += vv[j] * vv[j]; }
  #pragma unroll
  for (int m_ = 1; m_ < 64; m_ <<= 1) { s += __shfl_xor(s, m_); s2 += __shfl_xor(s2, m_); }
  float mean = s * (1.f / 512.f);
  float var = s2 * (1.f / 512.f) - mean * mean;
  float inv = rsqrtf(var + 1e-5f);
  #pragma unroll
  for (int j = 0; j < 8; ++j) {
    int c = lane * 8 + j;
    xln[(size_t)row * 512 + c] = f2bf((vv[j] - mean) * inv * gamma[c] + beta[c]);
  }
}

// ---------------- fused attention: per block = (b, h, 128 queries), 8 waves ----------------
__global__ __launch_bounds__(512) void attn_kernel(
    const unsigned short* __restrict__ qb, const unsigned short* __restrict__ kbuf,
    const unsigned short* __restrict__ vbuf, unsigned short* __restrict__ aout) {
  __shared__ unsigned short k_lds[256 * 64];   // [m][d]
  __shared__ unsigned short v_lds[64 * 256];   // [d][m]  (V^T)
  __shared__ unsigned short p_lds[8][16 * 256];
  const int tid = threadIdx.x, lane = tid & 63, w = tid >> 6;
  const int l15 = lane & 15, lhi = lane >> 4;
  const int b = blockIdx.z, h = blockIdx.y;
  const int q0 = blockIdx.x * 128;

  const char* ksrc = (const char*)(kbuf + ((size_t)(b * 8 + h)) * 256 * 64);
  const char* vsrc = (const char*)(vbuf + ((size_t)(b * 8 + h)) * 64 * 256);
  #pragma unroll
  for (int r = 0; r < 4; ++r) {
    int o = r * 8192 + tid * 16;
    gload16(ksrc + o, (char*)k_lds + r * 8192 + w * 1024);
    gload16(vsrc + o, (char*)v_lds + r * 8192 + w * 1024);
  }
  __syncthreads();

  const int qrow = q0 + w * 16 + l15;
  const unsigned short* qp = qb + (size_t)(b * 4096 + qrow) * 512 + h * 64 + lhi * 8;
  bf16x8 qf0 = *(const bf16x8*)qp;
  bf16x8 qf1 = *(const bf16x8*)(qp + 32);

  f32x4 s[16];
  #pragma unroll
  for (int t = 0; t < 16; ++t) {
    const unsigned short* kp = &k_lds[(t * 16 + l15) * 64 + lhi * 8];
    bf16x8 kf0 = *(const bf16x8*)kp;
    bf16x8 kf1 = *(const bf16x8*)(kp + 32);
    f32x4 a = {0.f, 0.f, 0.f, 0.f};
    a = MFMA16(qf0, kf0, a);
    a = MFMA16(qf1, kf1, a);
    s[t] = a;
  }

  #pragma unroll
  for (int r = 0; r < 4; ++r) {
    float mx = -1e30f;
    #pragma unroll
    for (int t = 0; t < 16; ++t) { s[t][r] *= 0.125f; mx = fmaxf(mx, s[t][r]); }
    #pragma unroll
    for (int m_ = 1; m_ < 16; m_ <<= 1) mx = fmaxf(mx, __shfl_xor(mx, m_));
    float sum = 0.f;
    #pragma unroll
    for (int t = 0; t < 16; ++t) { float pe = __expf(s[t][r] - mx); s[t][r] = pe; sum += pe; }
    #pragma unroll
    for (int m_ = 1; m_ < 16; m_ <<= 1) sum += __shfl_xor(sum, m_);
    float invs = 1.f / sum;
    #pragma unroll
    for (int t = 0; t < 16; ++t)
      p_lds[w][(lhi * 4 + r) * 256 + t * 16 + l15] = f2bf(s[t][r] * invs);
  }

  f32x4 o[4] = {};
  #pragma unroll
  for (int ks = 0; ks < 8; ++ks) {
    bf16x8 pf = *(const bf16x8*)&p_lds[w][l15 * 256 + ks * 32 + lhi * 8];
    #pragma unroll
    for (int n = 0; n < 4; ++n) {
      bf16x8 vf = *(const bf16x8*)&v_lds[(n * 16 + l15) * 256 + ks * 32 + lhi * 8];
      o[n] = MFMA16(pf, vf, o[n]);
    }
  }

  #pragma unroll
  for (int n = 0; n < 4; ++n)
    #pragma unroll
    for (int r = 0; r < 4; ++r)
      aout[(size_t)(b * 4096 + q0 + w * 16 + lhi * 4 + r) * 512 + h * 64 + n * 16 + l15] =
          f2bf(o[n][r]);
}

// ---------------- launch ----------------
extern "C" void kernel_launch(void* const* d_in, const int* in_sizes, int n_in,
                              void* d_out, int out_size, void* d_ws, size_t ws_size,
                              hipStream_t stream) {
  const float* x     = (const float*)d_in[0];
  const float* Wq    = (const float*)d_in[1];
  const float* bq    = (const float*)d_in[2];
  const float* Wkv   = (const float*)d_in[3];
  const float* bkv   = (const float*)d_in[4];
  const float* Wp    = (const float*)d_in[5];
  const float* bp    = (const float*)d_in[6];
  const float* Wsr   = (const float*)d_in[7];
  const float* bsr   = (const float*)d_in[8];
  const float* gamma = (const float*)d_in[9];
  const float* beta  = (const float*)d_in[10];

  char* ws = (char*)d_ws;
  unsigned short* xb   = (unsigned short*)(ws + 0);          // 32 MB (aliased: aout)
  unsigned short* qb   = (unsigned short*)(ws + 33554432);   // 32 MB
  unsigned short* wqt  = (unsigned short*)(ws + 67108864);   // 512 KB
  unsigned short* wkvt = (unsigned short*)(ws + 67633152);   // 1 MB
  unsigned short* wpt  = (unsigned short*)(ws + 68681728);   // 512 KB
  unsigned short* wsrt = (unsigned short*)(ws + 69206016);   // 8 MB
  float*          xr   = (float*)(ws + 77594624);            // 4 MB
  unsigned short* xln  = (unsigned short*)(ws + 81788928);   // 2 MB
  unsigned short* kbuf = (unsigned short*)(ws + 83886080);   // 2 MB
  unsigned short* vbuf = (unsigned short*)(ws + 85983232);   // 2 MB
  unsigned short* aout = xb;  // x no longer needed once attention runs

  pack_x_kernel<<<16384, 256, 0, stream>>>(x, xb);
  pack_w_kernel<<<20480, 256, 0, stream>>>(Wq, Wkv, Wp, Wsr, wqt, wkvt, wpt, wsrt);
  // Q projection: qb = xb @ WqT + bq (bf16 out)
  gemm_bf16<2, 2, 4, 4, 1, false><<<dim3(256, 4), 256, 0, stream>>>(
      xb, wqt, bq, qb, nullptr, nullptr, 32768, 512, 512, 512);
  // SR conv as gathered GEMM: xr = patches @ WsrT + bsr (fp32 out)
  gemm_bf16<2, 2, 2, 2, 0, true><<<dim3(32, 8), 256, 0, stream>>>(
      xb, wsrt, bsr, xr, nullptr, nullptr, 2048, 512, 8192, 512);
  ln_kernel<<<2048, 64, 0, stream>>>(xr, gamma, beta, xln);
  // KV projection with k / V^T scatter epilogue
  gemm_bf16<2, 2, 4, 4, 2, false><<<dim3(16, 8), 256, 0, stream>>>(
      xln, wkvt, bkv, nullptr, kbuf, vbuf, 2048, 1024, 512, 512);
  attn_kernel<<<dim3(32, 8, 8), 512, 0, stream>>>(qb, kbuf, vbuf, aout);
  // output projection (fp32 out to d_out)
  gemm_bf16<2, 2, 4, 4, 0, false><<<dim3(256, 4), 256, 0, stream>>>(
      aout, wpt, bp, (float*)d_out, nullptr, nullptr, 32768, 512, 512, 512);
}

// Round 2
// 212.456 us; speedup vs baseline: 1.4543x; 1.4543x over previous
//
#include <hip/hip_runtime.h>
#include <stdint.h>

typedef __attribute__((ext_vector_type(8))) short bf16x8;
typedef __attribute__((ext_vector_type(4))) float f32x4;

#define MFMA16(a,b,c) __builtin_amdgcn_mfma_f32_16x16x32_bf16(a,b,c,0,0,0)

typedef const __attribute__((address_space(1))) void GV;
typedef __attribute__((address_space(3))) void LV;

static __device__ __forceinline__ void gload16(const void* g, void* l) {
  __builtin_amdgcn_global_load_lds((GV*)g, (LV*)l, 16, 0, 0);
}

static __device__ __forceinline__ unsigned short f2bf(float f) {
  union { float f; unsigned u; } x; x.f = f;
  unsigned r = x.u + 0x7FFFu + ((x.u >> 16) & 1u);
  return (unsigned short)(r >> 16);
}

// ---------------- pack kernels ----------------
__global__ __launch_bounds__(256) void pack_x_kernel(
    const float* __restrict__ x, unsigned short* __restrict__ xb) {
  int i = blockIdx.x * 256 + threadIdx.x;           // 4 elements each
  float4 v = ((const float4*)x)[i];
  unsigned a0 = f2bf(v.x), a1 = f2bf(v.y), a2 = f2bf(v.z), a3 = f2bf(v.w);
  uint2 pk; pk.x = a0 | (a1 << 16); pk.y = a2 | (a3 << 16);
  ((uint2*)xb)[i] = pk;
}

__global__ __launch_bounds__(256) void pack_w_kernel(
    const float* __restrict__ Wq, const float* __restrict__ Wkv,
    const float* __restrict__ Wp, const float* __restrict__ Wsr,
    unsigned short* __restrict__ wqt, unsigned short* __restrict__ wkvt,
    unsigned short* __restrict__ wpt, unsigned short* __restrict__ wsrt) {
  int idx = blockIdx.x * 256 + threadIdx.x;         // total 5,242,880
  if (idx < 262144) {
    int n = idx >> 9, k = idx & 511;
    wqt[idx] = f2bf(Wq[k * 512 + n]);
  } else if (idx < 786432) {
    int j = idx - 262144; int n = j >> 9, k = j & 511;
    wkvt[j] = f2bf(Wkv[k * 1024 + n]);
  } else if (idx < 1048576) {
    int j = idx - 786432; int n = j >> 9, k = j & 511;
    wpt[j] = f2bf(Wp[k * 512 + n]);
  } else {
    int j = idx - 1048576;                          // wsrt[oc][r12][ic]
    int oc = j >> 13, rem = j & 8191;
    int r12 = rem >> 9, ic = rem & 511;
    wsrt[j] = f2bf(Wsr[oc * 8192 + ic * 16 + r12]);
  }
}

// ---------------- GEMM: C = A * Bt^T (+bias) ----------------
// MODE 0: fp32 row-major out (+bias)
// MODE 2: K/V fragment-layout scatter (+bias)
// MODE 3: conv split-K fp32 partial (no bias), out[(z*M+gm)*N+gn]
// MODE 4: Q fragment-layout scatter (+bias, *0.125)
template<int WM, int WN, int MREP, int NREP, int MODE, bool CONV, bool SWZ>
__global__ __launch_bounds__(256) void gemm_bf16(
    const unsigned short* __restrict__ A, const unsigned short* __restrict__ Bt,
    const float* __restrict__ bias, void* __restrict__ outp,
    unsigned short* __restrict__ out_k, unsigned short* __restrict__ out_v,
    int M, int N, int K, int lda, int Ksub) {
  constexpr int BM = WM * MREP * 16;
  constexpr int BN = WN * NREP * 16;
  constexpr int BK = 64;
  __shared__ unsigned short lds_a[BM * BK];
  __shared__ unsigned short lds_b[BN * BK];
  const int tid = threadIdx.x;
  const int lane = tid & 63, w = tid >> 6;
  const int wr = w / WN, wc = w % WN;
  const int l15 = lane & 15, lhi = lane >> 4;
  int mt, nt;
  if constexpr (SWZ) {
    int lin = blockIdx.x + blockIdx.y * gridDim.x;
    int nwg = gridDim.x * gridDim.y;
    int cpx = nwg >> 3;
    int s = (lin & 7) * cpx + (lin >> 3);
    int gdy = gridDim.y;
    mt = s / gdy; nt = s - mt * gdy;
  } else { mt = blockIdx.x; nt = blockIdx.y; }
  const int m0 = mt * BM;
  const int n0 = nt * BN;
  const int kbeg = blockIdx.z * Ksub;

  f32x4 acc[MREP][NREP] = {};
  constexpr int AR = (BM * BK * 2) / 4096;
  constexpr int BR = (BN * BK * 2) / 4096;

  for (int k0 = kbeg; k0 < kbeg + Ksub; k0 += BK) {
    #pragma unroll
    for (int r = 0; r < AR; ++r) {
      int o = r * 4096 + tid * 16;          // byte offset in lds_a
      int row = o >> 7;                     // 128 B per row (64 bf16)
      int kc = (o & 127) >> 1;
      const unsigned short* src;
      if constexpr (CONV) {
        int m = m0 + row;
        int bb = m >> 8, pix = m & 255;
        int oh = pix >> 4, ow = pix & 15;
        int r12 = k0 >> 9;
        int icc = (k0 & 511) + kc;
        int r1 = r12 >> 2, r2 = r12 & 3;
        int nn = (oh * 4 + r1) * 64 + ow * 4 + r2;
        src = A + ((size_t)(bb * 4096 + nn)) * 512 + icc;
      } else {
        src = A + (size_t)(m0 + row) * lda + k0 + kc;
      }
      gload16(src, (char*)lds_a + r * 4096 + w * 1024);
    }
    #pragma unroll
    for (int r = 0; r < BR; ++r) {
      int o = r * 4096 + tid * 16;
      int row = o >> 7;
      int kc = (o & 127) >> 1;
      const unsigned short* src = Bt + (size_t)(n0 + row) * K + k0 + kc;
      gload16(src, (char*)lds_b + r * 4096 + w * 1024);
    }
    __syncthreads();
    #pragma unroll
    for (int kk = 0; kk < BK; kk += 32) {
      bf16x8 af[MREP], bfr[NREP];
      #pragma unroll
      for (int m = 0; m < MREP; ++m)
        af[m] = *(const bf16x8*)&lds_a[(wr * MREP * 16 + m * 16 + l15) * BK + kk + lhi * 8];
      #pragma unroll
      for (int n = 0; n < NREP; ++n)
        bfr[n] = *(const bf16x8*)&lds_b[(wc * NREP * 16 + n * 16 + l15) * BK + kk + lhi * 8];
      #pragma unroll
      for (int m = 0; m < MREP; ++m)
        #pragma unroll
        for (int n = 0; n < NREP; ++n)
          acc[m][n] = MFMA16(af[m], bfr[n], acc[m][n]);
    }
    __syncthreads();
  }

  #pragma unroll
  for (int m = 0; m < MREP; ++m) {
    #pragma unroll
    for (int n = 0; n < NREP; ++n) {
      #pragma unroll
      for (int r = 0; r < 4; ++r) {
        int gm = m0 + wr * MREP * 16 + m * 16 + lhi * 4 + r;
        int gn = n0 + wc * NREP * 16 + n * 16 + l15;
        if constexpr (MODE == 0) {
          float v = acc[m][n][r] + bias[gn];
          ((float*)outp)[(size_t)gm * N + gn] = v;
        } else if constexpr (MODE == 3) {
          ((float*)outp)[((size_t)blockIdx.z * M + gm) * N + gn] = acc[m][n][r];
        } else if constexpr (MODE == 4) {
          float v = (acc[m][n][r] + bias[gn]) * 0.125f;
          int b_ = gm >> 12, n_ = gm & 4095;
          int hh = gn >> 6, d = gn & 63;
          int qt = n_ >> 4, half = d >> 5, dd = d & 31;
          int ln = (n_ & 15) | ((dd >> 3) << 4);
          ((unsigned short*)outp)[(size_t)(b_ * 8 + hh) * 262144 +
              (qt * 2 + half) * 512 + ln * 8 + (d & 7)] = f2bf(v);
        } else {  // MODE 2: K/V scatter
          float v = acc[m][n][r] + bias[gn];
          unsigned short bv = f2bf(v);
          int bb = gm >> 8, nr = gm & 255;
          if (gn < 512) {
            int hh = gn >> 6, d = gn & 63;
            int t = nr >> 4, half = d >> 5, dd = d & 31;
            int ln = (nr & 15) | ((dd >> 3) << 4);
            out_k[(size_t)(bb * 8 + hh) * 16384 +
                  (t * 2 + half) * 512 + ln * 8 + (d & 7)] = bv;
          } else {
            int c = gn - 512;
            int hh = c >> 6, d = c & 63;
            int nn = d >> 4, cl = d & 15;
            int ks = nr >> 5, lh = (nr >> 3) & 3;
            out_v[(size_t)(bb * 8 + hh) * 16384 +
                  (nn * 8 + ks) * 512 + (cl | (lh << 4)) * 8 + (nr & 7)] = bv;
          }
        }
      }
    }
  }
}

// ---------------- LayerNorm + split-K reduction + bias, one wave per row ----------------
__global__ __launch_bounds__(64) void ln_kernel(
    const float* __restrict__ part, const float* __restrict__ bsr,
    const float* __restrict__ gamma, const float* __restrict__ beta,
    unsigned short* __restrict__ xln) {
  const int row = blockIdx.x, lane = threadIdx.x;
  float vv[8];
  #pragma unroll
  for (int j = 0; j < 8; ++j) vv[j] = bsr[lane * 8 + j];
  #pragma unroll
  for (int p = 0; p < 8; ++p) {
    const float* pp = part + ((size_t)p * 2048 + row) * 512 + lane * 8;
    float4 a0 = *(const float4*)pp;
    float4 a1 = *(const float4*)(pp + 4);
    vv[0] += a0.x; vv[1] += a0.y; vv[2] += a0.z; vv[3] += a0.w;
    vv[4] += a1.x; vv[5] += a1.y; vv[6] += a1.z; vv[7] += a1.w;
  }
  float s = 0.f, s2 = 0.f;
  #pragma unroll
  for (int j = 0; j < 8; ++j) { s += vv[j]; s2 += vv[j] * vv[j]; }
  #pragma unroll
  for (int m_ = 1; m_ < 64; m_ <<= 1) { s += __shfl_xor(s, m_); s2 += __shfl_xor(s2, m_); }
  float mean = s * (1.f / 512.f);
  float var = s2 * (1.f / 512.f) - mean * mean;
  float inv = rsqrtf(var + 1e-5f);
  #pragma unroll
  for (int j = 0; j < 8; ++j) {
    int c = lane * 8 + j;
    xln[(size_t)row * 512 + c] = f2bf((vv[j] - mean) * inv * gamma[c] + beta[c]);
  }
}

// ---------------- fused attention: block = (b, h, 64 queries), 4 waves ----------------
// K/V/Q all pre-laid-out in MFMA fragment order: every LDS/global read is
// base + lane*16 (zero bank conflicts, linear global_load_lds staging).
__global__ __launch_bounds__(256) void attn_kernel(
    const unsigned short* __restrict__ qfrag, const unsigned short* __restrict__ kfrag,
    const unsigned short* __restrict__ vfrag, unsigned short* __restrict__ aout) {
  __shared__ unsigned short k_lds[16384];   // [t(16)][half(2)][lane(64)][8]
  __shared__ unsigned short v_lds[16384];   // [n(4)][ks(8)][lane(64)][8]
  const int tid = threadIdx.x, lane = tid & 63, w = tid >> 6;
  const int l15 = lane & 15, lhi = lane >> 4;
  const int b = blockIdx.z, h = blockIdx.y;
  const int bh = b * 8 + h;
  const char* kb_ = (const char*)(kfrag + (size_t)bh * 16384);
  const char* vb_ = (const char*)(vfrag + (size_t)bh * 16384);
  #pragma unroll
  for (int r = 0; r < 8; ++r) {
    gload16(kb_ + r * 4096 + tid * 16, (char*)k_lds + r * 4096 + w * 1024);
    gload16(vb_ + r * 4096 + tid * 16, (char*)v_lds + r * 4096 + w * 1024);
  }
  const int qt = blockIdx.x * 4 + w;
  const unsigned short* qbase = qfrag + (size_t)bh * 262144 + (size_t)qt * 1024;
  bf16x8 qf0 = *(const bf16x8*)(qbase + lane * 8);
  bf16x8 qf1 = *(const bf16x8*)(qbase + 512 + lane * 8);
  __syncthreads();

  // swapped QK^T: st[t][r] = S[q = l15][k = t*16 + lhi*4 + r]  (scale folded into Q)
  f32x4 st[16];
  #pragma unroll
  for (int t = 0; t < 16; ++t) {
    bf16x8 kf0 = *(const bf16x8*)&k_lds[t * 1024 + lane * 8];
    bf16x8 kf1 = *(const bf16x8*)&k_lds[t * 1024 + 512 + lane * 8];
    f32x4 a = {0.f, 0.f, 0.f, 0.f};
    a = MFMA16(kf0, qf0, a);
    a = MFMA16(kf1, qf1, a);
    st[t] = a;
  }

  float mx = -1e30f;
  #pragma unroll
  for (int t = 0; t < 16; ++t)
    mx = fmaxf(mx, fmaxf(fmaxf(st[t][0], st[t][1]), fmaxf(st[t][2], st[t][3])));
  mx = fmaxf(mx, __shfl_xor(mx, 16));
  mx = fmaxf(mx, __shfl_xor(mx, 32));

  float sum = 0.f;
  unsigned pk2[16][2];
  #pragma unroll
  for (int t = 0; t < 16; ++t) {
    float p0 = __expf(st[t][0] - mx), p1 = __expf(st[t][1] - mx);
    float p2 = __expf(st[t][2] - mx), p3 = __expf(st[t][3] - mx);
    sum += (p0 + p1) + (p2 + p3);
    unsigned r0, r1;
    asm("v_cvt_pk_bf16_f32 %0, %1, %2" : "=v"(r0) : "v"(p0), "v"(p1));
    asm("v_cvt_pk_bf16_f32 %0, %1, %2" : "=v"(r1) : "v"(p2), "v"(p3));
    pk2[t][0] = r0; pk2[t][1] = r1;
  }
  sum += __shfl_xor(sum, 16);
  sum += __shfl_xor(sum, 32);
  float invs = 1.f / sum;

  // redistribute P into PV A-fragment layout via 8 shuffles per k-slice
  const int srcA = l15 + (((2 * lhi) & 3) << 4);
  const int srcB = l15 + (((2 * lhi + 1) & 3) << 4);
  const bool hi2 = lhi >= 2;
  f32x4 o[4] = {};
  #pragma unroll
  for (int ks = 0; ks < 8; ++ks) {
    unsigned A0  = __shfl(pk2[2 * ks][0], srcA),     A0b = __shfl(pk2[2 * ks][1], srcA);
    unsigned A1  = __shfl(pk2[2 * ks + 1][0], srcA), A1b = __shfl(pk2[2 * ks + 1][1], srcA);
    unsigned B0  = __shfl(pk2[2 * ks][0], srcB),     B0b = __shfl(pk2[2 * ks][1], srcB);
    unsigned B1  = __shfl(pk2[2 * ks + 1][0], srcB), B1b = __shfl(pk2[2 * ks + 1][1], srcB);
    union { unsigned u[4]; bf16x8 v; } pu;
    pu.u[0] = hi2 ? A1 : A0;  pu.u[1] = hi2 ? A1b : A0b;
    pu.u[2] = hi2 ? B1 : B0;  pu.u[3] = hi2 ? B1b : B0b;
    #pragma unroll
    for (int n = 0; n < 4; ++n) {
      bf16x8 vf = *(const bf16x8*)&v_lds[(n * 8 + ks) * 512 + lane * 8];
      o[n] = MFMA16(pu.v, vf, o[n]);
    }
  }

  float inv0 = __shfl(invs, lhi * 4 + 0);
  float inv1 = __shfl(invs, lhi * 4 + 1);
  float inv2 = __shfl(invs, lhi * 4 + 2);
  float inv3 = __shfl(invs, lhi * 4 + 3);
  const int q0 = blockIdx.x * 64;
  #pragma unroll
  for (int n = 0; n < 4; ++n) {
    size_t base = (size_t)(b * 4096 + q0 + w * 16 + lhi * 4) * 512 + h * 64 + n * 16 + l15;
    aout[base]        = f2bf(o[n][0] * inv0);
    aout[base + 512]  = f2bf(o[n][1] * inv1);
    aout[base + 1024] = f2bf(o[n][2] * inv2);
    aout[base + 1536] = f2bf(o[n][3] * inv3);
  }
}

// ---------------- launch ----------------
extern "C" void kernel_launch(void* const* d_in, const int* in_sizes, int n_in,
                              void* d_out, int out_size, void* d_ws, size_t ws_size,
                              hipStream_t stream) {
  const float* x     = (const float*)d_in[0];
  const float* Wq    = (const float*)d_in[1];
  const float* bq    = (const float*)d_in[2];
  const float* Wkv   = (const float*)d_in[3];
  const float* bkv   = (const float*)d_in[4];
  const float* Wp    = (const float*)d_in[5];
  const float* bp    = (const float*)d_in[6];
  const float* Wsr   = (const float*)d_in[7];
  const float* bsr   = (const float*)d_in[8];
  const float* gamma = (const float*)d_in[9];
  const float* beta  = (const float*)d_in[10];

  char* ws = (char*)d_ws;
  unsigned short* xb    = (unsigned short*)(ws + 0);          // 32 MB (later: aout)
  float*          part  = (float*)(ws + 33554432);            // 32 MB (later: qfrag)
  unsigned short* qfrag = (unsigned short*)(ws + 33554432);
  unsigned short* wqt   = (unsigned short*)(ws + 67108864);   // 512 KB
  unsigned short* wkvt  = (unsigned short*)(ws + 67633152);   // 1 MB
  unsigned short* wpt   = (unsigned short*)(ws + 68681728);   // 512 KB
  unsigned short* wsrt  = (unsigned short*)(ws + 69206016);   // 8 MB
  unsigned short* xln   = (unsigned short*)(ws + 77594624);   // 2 MB
  unsigned short* kfrag = (unsigned short*)(ws + 79691776);   // 2 MB
  unsigned short* vfrag = (unsigned short*)(ws + 81788928);   // 2 MB
  unsigned short* aout  = xb;

  pack_x_kernel<<<16384, 256, 0, stream>>>(x, xb);
  pack_w_kernel<<<20480, 256, 0, stream>>>(Wq, Wkv, Wp, Wsr, wqt, wkvt, wpt, wsrt);
  // SR conv as gathered GEMM, split-K=8 -> fp32 partials
  gemm_bf16<2, 2, 2, 2, 3, true, false><<<dim3(32, 8, 8), 256, 0, stream>>>(
      xb, wsrt, nullptr, part, nullptr, nullptr, 2048, 512, 8192, 512, 1024);
  // LN fused with split-K reduce + conv bias
  ln_kernel<<<2048, 64, 0, stream>>>(part, bsr, gamma, beta, xln);
  // KV projection, epilogue scatters K/V into MFMA-fragment layout
  gemm_bf16<2, 2, 4, 4, 2, false, false><<<dim3(16, 8, 1), 256, 0, stream>>>(
      xln, wkvt, bkv, nullptr, kfrag, vfrag, 2048, 1024, 512, 512, 512);
  // Q projection (scaled, fragment layout), XCD-swizzled; overwrites `part`
  gemm_bf16<2, 2, 4, 4, 4, false, true><<<dim3(256, 4, 1), 256, 0, stream>>>(
      xb, wqt, bq, qfrag, nullptr, nullptr, 32768, 512, 512, 512, 512);
  attn_kernel<<<dim3(64, 8, 8), 256, 0, stream>>>(qfrag, kfrag, vfrag, aout);
  // output projection, XCD-swizzled
  gemm_bf16<2, 2, 4, 4, 0, false, true><<<dim3(256, 4, 1), 256, 0, stream>>>(
      aout, wpt, bp, (float*)d_out, nullptr, nullptr, 32768, 512, 512, 512, 512);
}

// Round 4
// 202.270 us; speedup vs baseline: 1.5276x; 1.0504x over previous
//
#include <hip/hip_runtime.h>
#include <stdint.h>

typedef __attribute__((ext_vector_type(8))) short bf16x8;
typedef __attribute__((ext_vector_type(4))) float f32x4;
typedef __attribute__((ext_vector_type(2))) unsigned u32x2;

#define MFMA16(a,b,c) __builtin_amdgcn_mfma_f32_16x16x32_bf16(a,b,c,0,0,0)

typedef const __attribute__((address_space(1))) void GV;
typedef __attribute__((address_space(3))) void LV;

static __device__ __forceinline__ void gload16(const void* g, void* l) {
  __builtin_amdgcn_global_load_lds((GV*)g, (LV*)l, 16, 0, 0);
}

static __device__ __forceinline__ unsigned short f2bf(float f) {
  union { float f; unsigned u; } x; x.f = f;
  unsigned r = x.u + 0x7FFFu + ((x.u >> 16) & 1u);
  return (unsigned short)(r >> 16);
}

static __device__ __forceinline__ float fast_exp2(float x) {
#if __has_builtin(__builtin_amdgcn_exp2f)
  return __builtin_amdgcn_exp2f(x);
#else
  return __expf(x * 0.6931471805599453f);
#endif
}

// ---------------- pack kernels ----------------
__global__ __launch_bounds__(256) void pack_x_kernel(
    const float* __restrict__ x, unsigned short* __restrict__ xb) {
  int i = blockIdx.x * 256 + threadIdx.x;           // 4 elements each
  float4 v = ((const float4*)x)[i];
  unsigned a0 = f2bf(v.x), a1 = f2bf(v.y), a2 = f2bf(v.z), a3 = f2bf(v.w);
  uint2 pk; pk.x = a0 | (a1 << 16); pk.y = a2 | (a3 << 16);
  ((uint2*)xb)[i] = pk;
}

__global__ __launch_bounds__(256) void pack_w_kernel(
    const float* __restrict__ Wq, const float* __restrict__ Wkv,
    const float* __restrict__ Wp, const float* __restrict__ Wsr,
    unsigned short* __restrict__ wqt, unsigned short* __restrict__ wkvt,
    unsigned short* __restrict__ wpt, unsigned short* __restrict__ wsrt) {
  int idx = blockIdx.x * 256 + threadIdx.x;         // total 5,242,880
  if (idx < 262144) {
    int n = idx >> 9, k = idx & 511;
    wqt[idx] = f2bf(Wq[k * 512 + n]);
  } else if (idx < 786432) {
    int j = idx - 262144; int n = j >> 9, k = j & 511;
    wkvt[j] = f2bf(Wkv[k * 1024 + n]);
  } else if (idx < 1048576) {
    int j = idx - 786432; int n = j >> 9, k = j & 511;
    wpt[j] = f2bf(Wp[k * 512 + n]);
  } else {
    int j = idx - 1048576;                          // wsrt[oc][r12][ic]
    int oc = j >> 13, rem = j & 8191;
    int r12 = rem >> 9, ic = rem & 511;
    wsrt[j] = f2bf(Wsr[oc * 8192 + ic * 16 + r12]);
  }
}

// ---------------- GEMM: C = A * Bt^T (+bias) ----------------
// MODE 0: fp32 row-major out (+bias)
// MODE 2: K/V fragment-layout scatter (+bias)
// MODE 3: conv split-K fp32 partial (no bias)
// MODE 4: Q fragment-layout scatter (+bias, * 0.125*log2e)
template<int WM, int WN, int MREP, int NREP, int MODE, bool CONV, bool SWZ>
__global__ __launch_bounds__(256) void gemm_bf16(
    const unsigned short* __restrict__ A, const unsigned short* __restrict__ Bt,
    const float* __restrict__ bias, void* __restrict__ outp,
    unsigned short* __restrict__ out_k, unsigned short* __restrict__ out_v,
    int M, int N, int K, int lda, int Ksub) {
  constexpr int BM = WM * MREP * 16;
  constexpr int BN = WN * NREP * 16;
  constexpr int BK = 64;
  __shared__ unsigned short lds_a[BM * BK];
  __shared__ unsigned short lds_b[BN * BK];
  const int tid = threadIdx.x;
  const int lane = tid & 63, w = tid >> 6;
  const int wr = w / WN, wc = w % WN;
  const int l15 = lane & 15, lhi = lane >> 4;
  int mt, nt;
  if constexpr (SWZ) {
    int lin = blockIdx.x + blockIdx.y * gridDim.x;
    int nwg = gridDim.x * gridDim.y;
    int cpx = nwg >> 3;
    int s = (lin & 7) * cpx + (lin >> 3);
    int gdy = gridDim.y;
    mt = s / gdy; nt = s - mt * gdy;
  } else { mt = blockIdx.x; nt = blockIdx.y; }
  const int m0 = mt * BM;
  const int n0 = nt * BN;
  const int kbeg = blockIdx.z * Ksub;

  f32x4 acc[MREP][NREP] = {};
  constexpr int AR = (BM * BK * 2) / 4096;
  constexpr int BR = (BN * BK * 2) / 4096;

  for (int k0 = kbeg; k0 < kbeg + Ksub; k0 += BK) {
    #pragma unroll
    for (int r = 0; r < AR; ++r) {
      int o = r * 4096 + tid * 16;          // byte offset in lds_a
      int row = o >> 7;                     // 128 B per row (64 bf16)
      int kc = (o & 127) >> 1;
      const unsigned short* src;
      if constexpr (CONV) {
        int m = m0 + row;
        int bb = m >> 8, pix = m & 255;
        int oh = pix >> 4, ow = pix & 15;
        int r12 = k0 >> 9;
        int icc = (k0 & 511) + kc;
        int r1 = r12 >> 2, r2 = r12 & 3;
        int nn = (oh * 4 + r1) * 64 + ow * 4 + r2;
        src = A + ((size_t)(bb * 4096 + nn)) * 512 + icc;
      } else {
        src = A + (size_t)(m0 + row) * lda + k0 + kc;
      }
      gload16(src, (char*)lds_a + r * 4096 + w * 1024);
    }
    #pragma unroll
    for (int r = 0; r < BR; ++r) {
      int o = r * 4096 + tid * 16;
      int row = o >> 7;
      int kc = (o & 127) >> 1;
      const unsigned short* src = Bt + (size_t)(n0 + row) * K + k0 + kc;
      gload16(src, (char*)lds_b + r * 4096 + w * 1024);
    }
    __syncthreads();
    #pragma unroll
    for (int kk = 0; kk < BK; kk += 32) {
      bf16x8 af[MREP], bfr[NREP];
      #pragma unroll
      for (int m = 0; m < MREP; ++m)
        af[m] = *(const bf16x8*)&lds_a[(wr * MREP * 16 + m * 16 + l15) * BK + kk + lhi * 8];
      #pragma unroll
      for (int n = 0; n < NREP; ++n)
        bfr[n] = *(const bf16x8*)&lds_b[(wc * NREP * 16 + n * 16 + l15) * BK + kk + lhi * 8];
      #pragma unroll
      for (int m = 0; m < MREP; ++m)
        #pragma unroll
        for (int n = 0; n < NREP; ++n)
          acc[m][n] = MFMA16(af[m], bfr[n], acc[m][n]);
    }
    __syncthreads();
  }

  #pragma unroll
  for (int m = 0; m < MREP; ++m) {
    #pragma unroll
    for (int n = 0; n < NREP; ++n) {
      #pragma unroll
      for (int r = 0; r < 4; ++r) {
        int gm = m0 + wr * MREP * 16 + m * 16 + lhi * 4 + r;
        int gn = n0 + wc * NREP * 16 + n * 16 + l15;
        if constexpr (MODE == 0) {
          float v = acc[m][n][r] + bias[gn];
          ((float*)outp)[(size_t)gm * N + gn] = v;
        } else if constexpr (MODE == 3) {
          ((float*)outp)[((size_t)blockIdx.z * M + gm) * N + gn] = acc[m][n][r];
        } else if constexpr (MODE == 4) {
          float v = (acc[m][n][r] + bias[gn]) * 0.18033688011112042f;  // 0.125*log2(e)
          int b_ = gm >> 12, n_ = gm & 4095;
          int hh = gn >> 6, d = gn & 63;
          int qt = n_ >> 4, half = d >> 5, dd = d & 31;
          int ln = (n_ & 15) | ((dd >> 3) << 4);
          ((unsigned short*)outp)[(size_t)(b_ * 8 + hh) * 262144 +
              (qt * 2 + half) * 512 + ln * 8 + (d & 7)] = f2bf(v);
        } else {  // MODE 2: K/V scatter
          float v = acc[m][n][r] + bias[gn];
          unsigned short bv = f2bf(v);
          int bb = gm >> 8, nr = gm & 255;
          if (gn < 512) {
            int hh = gn >> 6, d = gn & 63;
            int t = nr >> 4, half = d >> 5, dd = d & 31;
            int ln = (nr & 15) | ((dd >> 3) << 4);
            out_k[(size_t)(bb * 8 + hh) * 16384 +
                  (t * 2 + half) * 512 + ln * 8 + (d & 7)] = bv;
          } else {
            int c = gn - 512;
            int hh = c >> 6, d = c & 63;
            int nn = d >> 4, cl = d & 15;
            int ks = nr >> 5, lh = (nr >> 3) & 3;
            out_v[(size_t)(bb * 8 + hh) * 16384 +
                  (nn * 8 + ks) * 512 + (cl | (lh << 4)) * 8 + (nr & 7)] = bv;
          }
        }
      }
    }
  }
}

// ---------------- LayerNorm + split-K reduction + bias ----------------
__global__ __launch_bounds__(64) void ln_kernel(
    const float* __restrict__ part, const float* __restrict__ bsr,
    const float* __restrict__ gamma, const float* __restrict__ beta,
    unsigned short* __restrict__ xln) {
  const int row = blockIdx.x, lane = threadIdx.x;
  float vv[8];
  #pragma unroll
  for (int j = 0; j < 8; ++j) vv[j] = bsr[lane * 8 + j];
  #pragma unroll
  for (int p = 0; p < 8; ++p) {
    const float* pp = part + ((size_t)p * 2048 + row) * 512 + lane * 8;
    float4 a0 = *(const float4*)pp;
    float4 a1 = *(const float4*)(pp + 4);
    vv[0] += a0.x; vv[1] += a0.y; vv[2] += a0.z; vv[3] += a0.w;
    vv[4] += a1.x; vv[5] += a1.y; vv[6] += a1.z; vv[7] += a1.w;
  }
  float s = 0.f, s2 = 0.f;
  #pragma unroll
  for (int j = 0; j < 8; ++j) { s += vv[j]; s2 += vv[j] * vv[j]; }
  #pragma unroll
  for (int m_ = 1; m_ < 64; m_ <<= 1) { s += __shfl_xor(s, m_); s2 += __shfl_xor(s2, m_); }
  float mean = s * (1.f / 512.f);
  float var = s2 * (1.f / 512.f) - mean * mean;
  float inv = rsqrtf(var + 1e-5f);
  #pragma unroll
  for (int j = 0; j < 8; ++j) {
    int c = lane * 8 + j;
    xln[(size_t)row * 512 + c] = f2bf((vv[j] - mean) * inv * gamma[c] + beta[c]);
  }
}

// ---------------- fused attention: block = (b, h, 128 queries), 8 waves ----------------
// Fragment-order operands; no-max exp2-domain softmax; P redistributed to the
// PV A/B fragment layout via the (HW-verified) shfl path; PV = mfma(V, P).
__global__ __launch_bounds__(512, 4) void attn_kernel(
    const unsigned short* __restrict__ qfrag, const unsigned short* __restrict__ kfrag,
    const unsigned short* __restrict__ vfrag, unsigned short* __restrict__ aout) {
  __shared__ unsigned short k_lds[16384];   // [t(16)][half(2)][lane(64)][8]
  __shared__ unsigned short v_lds[16384];   // [n(4)][ks(8)][lane(64)][8]
  const int tid = threadIdx.x, lane = tid & 63, w = tid >> 6;
  const int l15 = lane & 15;
  const int b = blockIdx.z, h = blockIdx.y;
  const int bh = b * 8 + h;
  const char* kb_ = (const char*)(kfrag + (size_t)bh * 16384);
  const char* vb_ = (const char*)(vfrag + (size_t)bh * 16384);
  #pragma unroll
  for (int r = 0; r < 4; ++r) {
    gload16(kb_ + r * 8192 + tid * 16, (char*)k_lds + r * 8192 + w * 1024);
    gload16(vb_ + r * 8192 + tid * 16, (char*)v_lds + r * 8192 + w * 1024);
  }
  const int qt = blockIdx.x * 8 + w;
  const unsigned short* qbase = qfrag + (size_t)bh * 262144 + (size_t)qt * 1024;
  bf16x8 qf0 = *(const bf16x8*)(qbase + lane * 8);
  bf16x8 qf1 = *(const bf16x8*)(qbase + 512 + lane * 8);
  __syncthreads();

  // swapped QK^T: st[t] holds S2[k = t*16 + lhi*4 + r][q = l15]  (log2-domain)
  f32x4 st[16];
  #pragma unroll
  for (int t = 0; t < 16; ++t) {
    bf16x8 kf0 = *(const bf16x8*)&k_lds[t * 1024 + lane * 8];
    bf16x8 kf1 = *(const bf16x8*)&k_lds[t * 1024 + 512 + lane * 8];
    f32x4 a = {0.f, 0.f, 0.f, 0.f};
    a = MFMA16(kf0, qf0, a);
    a = MFMA16(kf1, qf1, a);
    st[t] = a;
  }

  // no-max softmax: p = 2^s2 ; sum over k (in-lane 64 + 2 cross-group shfl)
  float sum = 0.f;
  unsigned pk2[16][2];
  #pragma unroll
  for (int t = 0; t < 16; ++t) {
    float p0 = fast_exp2(st[t][0]), p1 = fast_exp2(st[t][1]);
    float p2 = fast_exp2(st[t][2]), p3 = fast_exp2(st[t][3]);
    sum += (p0 + p1) + (p2 + p3);
    unsigned r0, r1;
    asm("v_cvt_pk_bf16_f32 %0, %1, %2" : "=v"(r0) : "v"(p0), "v"(p1));
    asm("v_cvt_pk_bf16_f32 %0, %1, %2" : "=v"(r1) : "v"(p2), "v"(p3));
    pk2[t][0] = r0; pk2[t][1] = r1;
  }
  sum += __shfl_xor(sum, 16);
  sum += __shfl_xor(sum, 32);
  float invs = 1.f / sum;   // for q = l15 (lane-local for swapped-PV output)

  // redistribute P into A/B-fragment layout (verified shfl path);
  // PV as mfma(V, P) -> O[d][q=l15]
  const int lhi_ = lane >> 4;
  const int srcA = l15 + (((2 * lhi_) & 3) << 4);
  const int srcB = l15 + (((2 * lhi_ + 1) & 3) << 4);
  const bool hi2 = lhi_ >= 2;
  f32x4 o[4] = {};
  #pragma unroll
  for (int ks = 0; ks < 8; ++ks) {
    union { unsigned u[4]; bf16x8 v; } pu;
    unsigned A0 = __shfl(pk2[2 * ks][0], srcA),     A0b = __shfl(pk2[2 * ks][1], srcA);
    unsigned A1 = __shfl(pk2[2 * ks + 1][0], srcA), A1b = __shfl(pk2[2 * ks + 1][1], srcA);
    unsigned B0 = __shfl(pk2[2 * ks][0], srcB),     B0b = __shfl(pk2[2 * ks][1], srcB);
    unsigned B1 = __shfl(pk2[2 * ks + 1][0], srcB), B1b = __shfl(pk2[2 * ks + 1][1], srcB);
    pu.u[0] = hi2 ? A1 : A0;  pu.u[1] = hi2 ? A1b : A0b;
    pu.u[2] = hi2 ? B1 : B0;  pu.u[3] = hi2 ? B1b : B0b;
    #pragma unroll
    for (int n = 0; n < 4; ++n) {
      bf16x8 vf = *(const bf16x8*)&v_lds[(n * 8 + ks) * 512 + lane * 8];
      o[n] = MFMA16(vf, pu.v, o[n]);   // A=V (row=d), B=P (col=q) -> O[d][q]
    }
  }

  const int q0 = blockIdx.x * 128;
  const int lhi = lane >> 4;
  #pragma unroll
  for (int n = 0; n < 4; ++n) {
    float a0 = o[n][0] * invs, a1 = o[n][1] * invs;
    float a2 = o[n][2] * invs, a3 = o[n][3] * invs;
    unsigned w0, w1;
    asm("v_cvt_pk_bf16_f32 %0, %1, %2" : "=v"(w0) : "v"(a0), "v"(a1));
    asm("v_cvt_pk_bf16_f32 %0, %1, %2" : "=v"(w1) : "v"(a2), "v"(a3));
    u32x2 pr; pr[0] = w0; pr[1] = w1;
    size_t base = (size_t)(b * 4096 + q0 + w * 16 + l15) * 512 + h * 64 + n * 16 + lhi * 4;
    *(u32x2*)(aout + base) = pr;
  }
}

// ---------------- launch ----------------
extern "C" void kernel_launch(void* const* d_in, const int* in_sizes, int n_in,
                              void* d_out, int out_size, void* d_ws, size_t ws_size,
                              hipStream_t stream) {
  const float* x     = (const float*)d_in[0];
  const float* Wq    = (const float*)d_in[1];
  const float* bq    = (const float*)d_in[2];
  const float* Wkv   = (const float*)d_in[3];
  const float* bkv   = (const float*)d_in[4];
  const float* Wp    = (const float*)d_in[5];
  const float* bp    = (const float*)d_in[6];
  const float* Wsr   = (const float*)d_in[7];
  const float* bsr   = (const float*)d_in[8];
  const float* gamma = (const float*)d_in[9];
  const float* beta  = (const float*)d_in[10];

  char* ws = (char*)d_ws;
  unsigned short* xb    = (unsigned short*)(ws + 0);          // 32 MB (later: aout)
  float*          part  = (float*)(ws + 33554432);            // 32 MB (later: qfrag)
  unsigned short* qfrag = (unsigned short*)(ws + 33554432);
  unsigned short* wqt   = (unsigned short*)(ws + 67108864);   // 512 KB
  unsigned short* wkvt  = (unsigned short*)(ws + 67633152);   // 1 MB
  unsigned short* wpt   = (unsigned short*)(ws + 68681728);   // 512 KB
  unsigned short* wsrt  = (unsigned short*)(ws + 69206016);   // 8 MB
  unsigned short* xln   = (unsigned short*)(ws + 77594624);   // 2 MB
  unsigned short* kfrag = (unsigned short*)(ws + 79691776);   // 2 MB
  unsigned short* vfrag = (unsigned short*)(ws + 81788928);   // 2 MB
  unsigned short* aout  = xb;

  pack_x_kernel<<<16384, 256, 0, stream>>>(x, xb);
  pack_w_kernel<<<20480, 256, 0, stream>>>(Wq, Wkv, Wp, Wsr, wqt, wkvt, wpt, wsrt);
  // SR conv as gathered GEMM, split-K=8 -> fp32 partials
  gemm_bf16<2, 2, 2, 2, 3, true, false><<<dim3(32, 8, 8), 256, 0, stream>>>(
      xb, wsrt, nullptr, part, nullptr, nullptr, 2048, 512, 8192, 512, 1024);
  // LN fused with split-K reduce + conv bias
  ln_kernel<<<2048, 64, 0, stream>>>(part, bsr, gamma, beta, xln);
  // KV projection, epilogue scatters K/V into MFMA-fragment layout
  gemm_bf16<2, 2, 4, 4, 2, false, false><<<dim3(16, 8, 1), 256, 0, stream>>>(
      xln, wkvt, bkv, nullptr, kfrag, vfrag, 2048, 1024, 512, 512, 512);
  // Q projection (scaled by 0.125*log2e, fragment layout); overwrites `part`
  gemm_bf16<2, 2, 4, 4, 4, false, true><<<dim3(256, 4, 1), 256, 0, stream>>>(
      xb, wqt, bq, qfrag, nullptr, nullptr, 32768, 512, 512, 512, 512);
  attn_kernel<<<dim3(32, 8, 8), 512, 0, stream>>>(qfrag, kfrag, vfrag, aout);
  // output projection, XCD-swizzled
  gemm_bf16<2, 2, 4, 4, 0, false, true><<<dim3(256, 4, 1), 256, 0, stream>>>(
      aout, wpt, bp, (float*)d_out, nullptr, nullptr, 32768, 512, 512, 512, 512);
}

// Round 5
// 179.226 us; speedup vs baseline: 1.7240x; 1.1286x over previous
//
#include <hip/hip_runtime.h>
#include <stdint.h>

typedef __attribute__((ext_vector_type(8))) short bf16x8;
typedef __attribute__((ext_vector_type(4))) float f32x4;
typedef __attribute__((ext_vector_type(2))) unsigned u32x2;

#define MFMA16(a,b,c) __builtin_amdgcn_mfma_f32_16x16x32_bf16(a,b,c,0,0,0)

typedef const __attribute__((address_space(1))) void GV;
typedef __attribute__((address_space(3))) void LV;

static __device__ __forceinline__ void gload16(const void* g, void* l) {
  __builtin_amdgcn_global_load_lds((GV*)g, (LV*)l, 16, 0, 0);
}

static __device__ __forceinline__ unsigned short f2bf(float f) {
  union { float f; unsigned u; } x; x.f = f;
  unsigned r = x.u + 0x7FFFu + ((x.u >> 16) & 1u);
  return (unsigned short)(r >> 16);
}

static __device__ __forceinline__ float fast_exp2(float x) {
#if __has_builtin(__builtin_amdgcn_exp2f)
  return __builtin_amdgcn_exp2f(x);
#else
  return __expf(x * 0.6931471805599453f);
#endif
}

// ---------------- pack kernels ----------------
__global__ __launch_bounds__(256) void pack_x_kernel(
    const float* __restrict__ x, unsigned short* __restrict__ xb) {
  int i = blockIdx.x * 256 + threadIdx.x;           // 4 elements each
  float4 v = ((const float4*)x)[i];
  unsigned a0 = f2bf(v.x), a1 = f2bf(v.y), a2 = f2bf(v.z), a3 = f2bf(v.w);
  uint2 pk; pk.x = a0 | (a1 << 16); pk.y = a2 | (a3 << 16);
  ((uint2*)xb)[i] = pk;
}

__global__ __launch_bounds__(256) void pack_w_kernel(
    const float* __restrict__ Wq, const float* __restrict__ Wkv,
    const float* __restrict__ Wp, const float* __restrict__ Wsr,
    unsigned short* __restrict__ wqt, unsigned short* __restrict__ wkvt,
    unsigned short* __restrict__ wpt, unsigned short* __restrict__ wsrt) {
  int idx = blockIdx.x * 256 + threadIdx.x;         // total 5,242,880
  if (idx < 262144) {
    int n = idx >> 9, k = idx & 511;
    wqt[idx] = f2bf(Wq[k * 512 + n]);
  } else if (idx < 786432) {
    int j = idx - 262144; int n = j >> 9, k = j & 511;
    wkvt[j] = f2bf(Wkv[k * 1024 + n]);
  } else if (idx < 1048576) {
    int j = idx - 786432; int n = j >> 9, k = j & 511;
    wpt[j] = f2bf(Wp[k * 512 + n]);
  } else {
    int j = idx - 1048576;                          // wsrt[oc][r12][ic]
    int oc = j >> 13, rem = j & 8191;
    int r12 = rem >> 9, ic = rem & 511;
    wsrt[j] = f2bf(Wsr[oc * 8192 + ic * 16 + r12]);
  }
}

// ---------------- GEMM: C = A * Bt^T (+bias) ----------------
// Double-buffered LDS, 1 barrier/K-step (stage-early, drain-late),
// T2 XOR-swizzle via pre-swizzled global source + swizzled ds_read,
// T5 setprio around the MFMA cluster.
// MODE 0: fp32 row-major out (+bias)
// MODE 2: K/V fragment-layout scatter (+bias)
// MODE 3: conv split-K fp32 partial (no bias)
// MODE 4: Q fragment-layout scatter (+bias, * 0.125*log2e)
template<int WM, int WN, int MREP, int NREP, int MODE, bool CONV, bool SWZ>
__global__ __launch_bounds__(256) void gemm_bf16(
    const unsigned short* __restrict__ A, const unsigned short* __restrict__ Bt,
    const float* __restrict__ bias, void* __restrict__ outp,
    unsigned short* __restrict__ out_k, unsigned short* __restrict__ out_v,
    int M, int N, int K, int lda, int Ksub) {
  constexpr int BM = WM * MREP * 16;
  constexpr int BN = WN * NREP * 16;
  constexpr int BK = 64;
  constexpr int ABYTES = BM * BK * 2;
  constexpr int BBYTES = BN * BK * 2;
  __shared__ unsigned short lds_a[2 * BM * BK];
  __shared__ unsigned short lds_b[2 * BN * BK];
  const int tid = threadIdx.x;
  const int lane = tid & 63, w = tid >> 6;
  const int wr = w / WN, wc = w % WN;
  const int l15 = lane & 15, lhi = lane >> 4;
  const int xmask = (l15 & 7) << 4;            // read-side byte swizzle
  const int smask = ((tid >> 3) & 7) << 3;     // stage-side element swizzle
  int mt, nt_;
  if constexpr (SWZ) {
    int lin = blockIdx.x + blockIdx.y * gridDim.x;
    int nwg = gridDim.x * gridDim.y;
    int cpx = nwg >> 3;
    int s = (lin & 7) * cpx + (lin >> 3);
    int gdy = gridDim.y;
    mt = s / gdy; nt_ = s - mt * gdy;
  } else { mt = blockIdx.x; nt_ = blockIdx.y; }
  const int m0 = mt * BM;
  const int n0 = nt_ * BN;
  const int kbeg = blockIdx.z * Ksub;

  f32x4 acc[MREP][NREP] = {};
  constexpr int AR = ABYTES / 4096;
  constexpr int BR = BBYTES / 4096;

  auto stage = [&](int buf, int k0) {
    #pragma unroll
    for (int r = 0; r < AR; ++r) {
      int o = r * 4096 + tid * 16;          // byte offset within A buffer
      int row = o >> 7;                     // 128 B per row (64 bf16)
      int kc = (((o & 127) >> 1)) ^ smask;  // inverse-swizzled source column
      const unsigned short* src;
      if constexpr (CONV) {
        int m = m0 + row;
        int bb = m >> 8, pix = m & 255;
        int oh = pix >> 4, ow = pix & 15;
        int r12 = k0 >> 9;
        int icc = (k0 & 511) + kc;
        int r1 = r12 >> 2, r2 = r12 & 3;
        int nn = (oh * 4 + r1) * 64 + ow * 4 + r2;
        src = A + ((size_t)(bb * 4096 + nn)) * 512 + icc;
      } else {
        src = A + (size_t)(m0 + row) * lda + k0 + kc;
      }
      gload16(src, (char*)lds_a + buf * ABYTES + r * 4096 + w * 1024);
    }
    #pragma unroll
    for (int r = 0; r < BR; ++r) {
      int o = r * 4096 + tid * 16;
      int row = o >> 7;
      int kc = (((o & 127) >> 1)) ^ smask;
      const unsigned short* src = Bt + (size_t)(n0 + row) * K + k0 + kc;
      gload16(src, (char*)lds_b + buf * BBYTES + r * 4096 + w * 1024);
    }
  };

  auto compute = [&](int buf) {
    const char* pa = (const char*)lds_a + buf * ABYTES;
    const char* pb = (const char*)lds_b + buf * BBYTES;
    #pragma unroll
    for (int kk = 0; kk < BK; kk += 32) {
      bf16x8 af[MREP], bfr[NREP];
      #pragma unroll
      for (int m = 0; m < MREP; ++m)
        af[m] = *(const bf16x8*)(pa + (wr * MREP * 16 + m * 16 + l15) * (BK * 2)
                                 + (((kk << 1) + (lhi << 4)) ^ xmask));
      #pragma unroll
      for (int n = 0; n < NREP; ++n)
        bfr[n] = *(const bf16x8*)(pb + (wc * NREP * 16 + n * 16 + l15) * (BK * 2)
                                  + (((kk << 1) + (lhi << 4)) ^ xmask));
      __builtin_amdgcn_s_setprio(1);
      #pragma unroll
      for (int m = 0; m < MREP; ++m)
        #pragma unroll
        for (int n = 0; n < NREP; ++n)
          acc[m][n] = MFMA16(af[m], bfr[n], acc[m][n]);
      __builtin_amdgcn_s_setprio(0);
    }
  };

  const int nsteps = Ksub / BK;   // always even here (8 or 16)
  stage(0, kbeg);
  __syncthreads();
  for (int t = 0; t < nsteps; t += 2) {
    if (t + 1 < nsteps) stage(1, kbeg + (t + 1) * BK);
    compute(0);
    asm volatile("s_waitcnt vmcnt(0)" ::: "memory");
    __builtin_amdgcn_s_barrier();
    if (t + 2 < nsteps) stage(0, kbeg + (t + 2) * BK);
    compute(1);
    if (t + 2 < nsteps) {
      asm volatile("s_waitcnt vmcnt(0)" ::: "memory");
      __builtin_amdgcn_s_barrier();
    }
  }

  #pragma unroll
  for (int m = 0; m < MREP; ++m) {
    #pragma unroll
    for (int n = 0; n < NREP; ++n) {
      #pragma unroll
      for (int r = 0; r < 4; ++r) {
        int gm = m0 + wr * MREP * 16 + m * 16 + lhi * 4 + r;
        int gn = n0 + wc * NREP * 16 + n * 16 + l15;
        if constexpr (MODE == 0) {
          float v = acc[m][n][r] + bias[gn];
          ((float*)outp)[(size_t)gm * N + gn] = v;
        } else if constexpr (MODE == 3) {
          ((float*)outp)[((size_t)blockIdx.z * M + gm) * N + gn] = acc[m][n][r];
        } else if constexpr (MODE == 4) {
          float v = (acc[m][n][r] + bias[gn]) * 0.18033688011112042f;  // 0.125*log2(e)
          int b_ = gm >> 12, n_ = gm & 4095;
          int hh = gn >> 6, d = gn & 63;
          int qt = n_ >> 4, half = d >> 5, dd = d & 31;
          int ln = (n_ & 15) | ((dd >> 3) << 4);
          ((unsigned short*)outp)[(size_t)(b_ * 8 + hh) * 262144 +
              (qt * 2 + half) * 512 + ln * 8 + (d & 7)] = f2bf(v);
        } else {  // MODE 2: K/V scatter
          float v = acc[m][n][r] + bias[gn];
          unsigned short bv = f2bf(v);
          int bb = gm >> 8, nr = gm & 255;
          if (gn < 512) {
            int hh = gn >> 6, d = gn & 63;
            int t_ = nr >> 4, half = d >> 5, dd = d & 31;
            int ln = (nr & 15) | ((dd >> 3) << 4);
            out_k[(size_t)(bb * 8 + hh) * 16384 +
                  (t_ * 2 + half) * 512 + ln * 8 + (d & 7)] = bv;
          } else {
            int c = gn - 512;
            int hh = c >> 6, d = c & 63;
            int nn = d >> 4, cl = d & 15;
            int ks = nr >> 5, lh = (nr >> 3) & 3;
            out_v[(size_t)(bb * 8 + hh) * 16384 +
                  (nn * 8 + ks) * 512 + (cl | (lh << 4)) * 8 + (nr & 7)] = bv;
          }
        }
      }
    }
  }
}

// ---------------- LayerNorm + split-K reduction + bias ----------------
__global__ __launch_bounds__(64) void ln_kernel(
    const float* __restrict__ part, const float* __restrict__ bsr,
    const float* __restrict__ gamma, const float* __restrict__ beta,
    unsigned short* __restrict__ xln) {
  const int row = blockIdx.x, lane = threadIdx.x;
  float vv[8];
  #pragma unroll
  for (int j = 0; j < 8; ++j) vv[j] = bsr[lane * 8 + j];
  #pragma unroll
  for (int p = 0; p < 8; ++p) {
    const float* pp = part + ((size_t)p * 2048 + row) * 512 + lane * 8;
    float4 a0 = *(const float4*)pp;
    float4 a1 = *(const float4*)(pp + 4);
    vv[0] += a0.x; vv[1] += a0.y; vv[2] += a0.z; vv[3] += a0.w;
    vv[4] += a1.x; vv[5] += a1.y; vv[6] += a1.z; vv[7] += a1.w;
  }
  float s = 0.f, s2 = 0.f;
  #pragma unroll
  for (int j = 0; j < 8; ++j) { s += vv[j]; s2 += vv[j] * vv[j]; }
  #pragma unroll
  for (int m_ = 1; m_ < 64; m_ <<= 1) { s += __shfl_xor(s, m_); s2 += __shfl_xor(s2, m_); }
  float mean = s * (1.f / 512.f);
  float var = s2 * (1.f / 512.f) - mean * mean;
  float inv = rsqrtf(var + 1e-5f);
  #pragma unroll
  for (int j = 0; j < 8; ++j) {
    int c = lane * 8 + j;
    xln[(size_t)row * 512 + c] = f2bf((vv[j] - mean) * inv * gamma[c] + beta[c]);
  }
}

// ---------------- fused attention: block = (b, h, 128 queries), 8 waves ----------------
__global__ __launch_bounds__(512, 4) void attn_kernel(
    const unsigned short* __restrict__ qfrag, const unsigned short* __restrict__ kfrag,
    const unsigned short* __restrict__ vfrag, unsigned short* __restrict__ aout) {
  __shared__ unsigned short k_lds[16384];   // [t(16)][half(2)][lane(64)][8]
  __shared__ unsigned short v_lds[16384];   // [n(4)][ks(8)][lane(64)][8]
  const int tid = threadIdx.x, lane = tid & 63, w = tid >> 6;
  const int l15 = lane & 15;
  const int b = blockIdx.z, h = blockIdx.y;
  const int bh = b * 8 + h;
  const char* kb_ = (const char*)(kfrag + (size_t)bh * 16384);
  const char* vb_ = (const char*)(vfrag + (size_t)bh * 16384);
  #pragma unroll
  for (int r = 0; r < 4; ++r) {
    gload16(kb_ + r * 8192 + tid * 16, (char*)k_lds + r * 8192 + w * 1024);
    gload16(vb_ + r * 8192 + tid * 16, (char*)v_lds + r * 8192 + w * 1024);
  }
  const int qt = blockIdx.x * 8 + w;
  const unsigned short* qbase = qfrag + (size_t)bh * 262144 + (size_t)qt * 1024;
  bf16x8 qf0 = *(const bf16x8*)(qbase + lane * 8);
  bf16x8 qf1 = *(const bf16x8*)(qbase + 512 + lane * 8);
  __syncthreads();

  // swapped QK^T: st[t] holds S2[k = t*16 + lhi*4 + r][q = l15]  (log2-domain)
  f32x4 st[16];
  #pragma unroll
  for (int t = 0; t < 16; ++t) {
    bf16x8 kf0 = *(const bf16x8*)&k_lds[t * 1024 + lane * 8];
    bf16x8 kf1 = *(const bf16x8*)&k_lds[t * 1024 + 512 + lane * 8];
    f32x4 a = {0.f, 0.f, 0.f, 0.f};
    a = MFMA16(kf0, qf0, a);
    a = MFMA16(kf1, qf1, a);
    st[t] = a;
  }

  // no-max softmax: p = 2^s2 ; sum over k (in-lane 64 + 2 cross-group shfl)
  float sum = 0.f;
  unsigned pk2[16][2];
  #pragma unroll
  for (int t = 0; t < 16; ++t) {
    float p0 = fast_exp2(st[t][0]), p1 = fast_exp2(st[t][1]);
    float p2 = fast_exp2(st[t][2]), p3 = fast_exp2(st[t][3]);
    sum += (p0 + p1) + (p2 + p3);
    unsigned r0, r1;
    asm("v_cvt_pk_bf16_f32 %0, %1, %2" : "=v"(r0) : "v"(p0), "v"(p1));
    asm("v_cvt_pk_bf16_f32 %0, %1, %2" : "=v"(r1) : "v"(p2), "v"(p3));
    pk2[t][0] = r0; pk2[t][1] = r1;
  }
  sum += __shfl_xor(sum, 16);
  sum += __shfl_xor(sum, 32);
  float invs = 1.f / sum;   // for q = l15 (lane-local for swapped-PV output)

  // redistribute P into A/B-fragment layout (verified shfl path);
  // PV as mfma(V, P) -> O[d][q=l15]
  const int lhi_ = lane >> 4;
  const int srcA = l15 + (((2 * lhi_) & 3) << 4);
  const int srcB = l15 + (((2 * lhi_ + 1) & 3) << 4);
  const bool hi2 = lhi_ >= 2;
  f32x4 o[4] = {};
  #pragma unroll
  for (int ks = 0; ks < 8; ++ks) {
    union { unsigned u[4]; bf16x8 v; } pu;
    unsigned A0 = __shfl(pk2[2 * ks][0], srcA),     A0b = __shfl(pk2[2 * ks][1], srcA);
    unsigned A1 = __shfl(pk2[2 * ks + 1][0], srcA), A1b = __shfl(pk2[2 * ks + 1][1], srcA);
    unsigned B0 = __shfl(pk2[2 * ks][0], srcB),     B0b = __shfl(pk2[2 * ks][1], srcB);
    unsigned B1 = __shfl(pk2[2 * ks + 1][0], srcB), B1b = __shfl(pk2[2 * ks + 1][1], srcB);
    pu.u[0] = hi2 ? A1 : A0;  pu.u[1] = hi2 ? A1b : A0b;
    pu.u[2] = hi2 ? B1 : B0;  pu.u[3] = hi2 ? B1b : B0b;
    #pragma unroll
    for (int n = 0; n < 4; ++n) {
      bf16x8 vf = *(const bf16x8*)&v_lds[(n * 8 + ks) * 512 + lane * 8];
      o[n] = MFMA16(vf, pu.v, o[n]);   // A=V (row=d), B=P (col=q) -> O[d][q]
    }
  }

  const int q0 = blockIdx.x * 128;
  const int lhi = lane >> 4;
  #pragma unroll
  for (int n = 0; n < 4; ++n) {
    float a0 = o[n][0] * invs, a1 = o[n][1] * invs;
    float a2 = o[n][2] * invs, a3 = o[n][3] * invs;
    unsigned w0, w1;
    asm("v_cvt_pk_bf16_f32 %0, %1, %2" : "=v"(w0) : "v"(a0), "v"(a1));
    asm("v_cvt_pk_bf16_f32 %0, %1, %2" : "=v"(w1) : "v"(a2), "v"(a3));
    u32x2 pr; pr[0] = w0; pr[1] = w1;
    size_t base = (size_t)(b * 4096 + q0 + w * 16 + l15) * 512 + h * 64 + n * 16 + lhi * 4;
    *(u32x2*)(aout + base) = pr;
  }
}

// ---------------- launch ----------------
extern "C" void kernel_launch(void* const* d_in, const int* in_sizes, int n_in,
                              void* d_out, int out_size, void* d_ws, size_t ws_size,
                              hipStream_t stream) {
  const float* x     = (const float*)d_in[0];
  const float* Wq    = (const float*)d_in[1];
  const float* bq    = (const float*)d_in[2];
  const float* Wkv   = (const float*)d_in[3];
  const float* bkv   = (const float*)d_in[4];
  const float* Wp    = (const float*)d_in[5];
  const float* bp    = (const float*)d_in[6];
  const float* Wsr   = (const float*)d_in[7];
  const float* bsr   = (const float*)d_in[8];
  const float* gamma = (const float*)d_in[9];
  const float* beta  = (const float*)d_in[10];

  char* ws = (char*)d_ws;
  unsigned short* xb    = (unsigned short*)(ws + 0);          // 32 MB (later: aout)
  float*          part  = (float*)(ws + 33554432);            // 32 MB (later: qfrag)
  unsigned short* qfrag = (unsigned short*)(ws + 33554432);
  unsigned short* wqt   = (unsigned short*)(ws + 67108864);   // 512 KB
  unsigned short* wkvt  = (unsigned short*)(ws + 67633152);   // 1 MB
  unsigned short* wpt   = (unsigned short*)(ws + 68681728);   // 512 KB
  unsigned short* wsrt  = (unsigned short*)(ws + 69206016);   // 8 MB
  unsigned short* xln   = (unsigned short*)(ws + 77594624);   // 2 MB
  unsigned short* kfrag = (unsigned short*)(ws + 79691776);   // 2 MB
  unsigned short* vfrag = (unsigned short*)(ws + 81788928);   // 2 MB
  unsigned short* aout  = xb;

  pack_x_kernel<<<16384, 256, 0, stream>>>(x, xb);
  pack_w_kernel<<<20480, 256, 0, stream>>>(Wq, Wkv, Wp, Wsr, wqt, wkvt, wpt, wsrt);
  // SR conv as gathered GEMM, split-K=8 -> fp32 partials
  gemm_bf16<2, 2, 2, 2, 3, true, false><<<dim3(32, 8, 8), 256, 0, stream>>>(
      xb, wsrt, nullptr, part, nullptr, nullptr, 2048, 512, 8192, 512, 1024);
  // LN fused with split-K reduce + conv bias
  ln_kernel<<<2048, 64, 0, stream>>>(part, bsr, gamma, beta, xln);
  // KV projection (64x128 tile -> 256 blocks), fragment-layout scatter
  gemm_bf16<2, 2, 2, 4, 2, false, false><<<dim3(32, 8, 1), 256, 0, stream>>>(
      xln, wkvt, bkv, nullptr, kfrag, vfrag, 2048, 1024, 512, 512, 512);
  // Q projection (scaled by 0.125*log2e, fragment layout); overwrites `part`
  gemm_bf16<2, 2, 4, 4, 4, false, true><<<dim3(256, 4, 1), 256, 0, stream>>>(
      xb, wqt, bq, qfrag, nullptr, nullptr, 32768, 512, 512, 512, 512);
  attn_kernel<<<dim3(32, 8, 8), 512, 0, stream>>>(qfrag, kfrag, vfrag, aout);
  // output projection, XCD-swizzled
  gemm_bf16<2, 2, 4, 4, 0, false, true><<<dim3(256, 4, 1), 256, 0, stream>>>(
      aout, wpt, bp, (float*)d_out, nullptr, nullptr, 32768, 512, 512, 512, 512);
}

// Round 6
// 168.716 us; speedup vs baseline: 1.8314x; 1.0623x over previous
//
#include <hip/hip_runtime.h>
#include <stdint.h>

typedef __attribute__((ext_vector_type(8))) short bf16x8;
typedef __attribute__((ext_vector_type(4))) float f32x4;
typedef __attribute__((ext_vector_type(2))) unsigned u32x2;

#define MFMA16(a,b,c) __builtin_amdgcn_mfma_f32_16x16x32_bf16(a,b,c,0,0,0)

typedef const __attribute__((address_space(1))) void GV;
typedef __attribute__((address_space(3))) void LV;

static __device__ __forceinline__ void gload16(const void* g, void* l) {
  __builtin_amdgcn_global_load_lds((GV*)g, (LV*)l, 16, 0, 0);
}

static __device__ __forceinline__ unsigned short f2bf(float f) {
  union { float f; unsigned u; } x; x.f = f;
  unsigned r = x.u + 0x7FFFu + ((x.u >> 16) & 1u);
  return (unsigned short)(r >> 16);
}

static __device__ __forceinline__ float fast_exp2(float x) {
#if __has_builtin(__builtin_amdgcn_exp2f)
  return __builtin_amdgcn_exp2f(x);
#else
  return __expf(x * 0.6931471805599453f);
#endif
}

// ---------------- pack kernels ----------------
__global__ __launch_bounds__(256) void pack_x_kernel(
    const float* __restrict__ x, unsigned short* __restrict__ xb) {
  int i = blockIdx.x * 256 + threadIdx.x;           // 4 elements each
  float4 v = ((const float4*)x)[i];
  unsigned a0 = f2bf(v.x), a1 = f2bf(v.y), a2 = f2bf(v.z), a3 = f2bf(v.w);
  uint2 pk; pk.x = a0 | (a1 << 16); pk.y = a2 | (a3 << 16);
  ((uint2*)xb)[i] = pk;
}

__global__ __launch_bounds__(256) void pack_w_kernel(
    const float* __restrict__ Wq, const float* __restrict__ Wkv,
    const float* __restrict__ Wp, const float* __restrict__ Wsr,
    unsigned short* __restrict__ wqt, unsigned short* __restrict__ wkvt,
    unsigned short* __restrict__ wpt, unsigned short* __restrict__ wsrt) {
  int idx = blockIdx.x * 256 + threadIdx.x;         // total 5,242,880
  if (idx < 262144) {
    int n = idx >> 9, k = idx & 511;
    wqt[idx] = f2bf(Wq[k * 512 + n]);
  } else if (idx < 786432) {
    int j = idx - 262144; int n = j >> 9, k = j & 511;
    wkvt[j] = f2bf(Wkv[k * 1024 + n]);
  } else if (idx < 1048576) {
    int j = idx - 786432; int n = j >> 9, k = j & 511;
    wpt[j] = f2bf(Wp[k * 512 + n]);
  } else {
    int j = idx - 1048576;                          // wsrt[oc][r12][ic]
    int oc = j >> 13, rem = j & 8191;
    int r12 = rem >> 9, ic = rem & 511;
    wsrt[j] = f2bf(Wsr[oc * 8192 + ic * 16 + r12]);
  }
}

// ---------------- GEMM: C = A * Bt^T (+bias) ----------------
// Double-buffered LDS with COUNTED vmcnt pipeline: stage(t+1) is issued, then
// s_waitcnt vmcnt(NL) guarantees stage(t) landed while t+1's loads stay in
// flight across both barriers and the whole compute phase (T4). T2 XOR-swizzle
// (pre-swizzled global source + swizzled ds_read), T5 setprio around MFMA.
// MODE 0: fp32 row-major out (+bias)
// MODE 2: K/V fragment-layout scatter (+bias)
// MODE 3: conv split-K fp32 partial (no bias)
// MODE 4: Q fragment-layout scatter (+bias, * 0.125*log2e)
template<int WM, int WN, int MREP, int NREP, int MODE, bool CONV, bool SWZ>
__global__ __launch_bounds__(256) void gemm_bf16(
    const unsigned short* __restrict__ A, const unsigned short* __restrict__ Bt,
    const float* __restrict__ bias, void* __restrict__ outp,
    unsigned short* __restrict__ out_k, unsigned short* __restrict__ out_v,
    int M, int N, int K, int lda, int Ksub) {
  constexpr int BM = WM * MREP * 16;
  constexpr int BN = WN * NREP * 16;
  constexpr int BK = 64;
  constexpr int ABYTES = BM * BK * 2;
  constexpr int BBYTES = BN * BK * 2;
  __shared__ unsigned short lds_a[2 * BM * BK];
  __shared__ unsigned short lds_b[2 * BN * BK];
  const int tid = threadIdx.x;
  const int lane = tid & 63, w = tid >> 6;
  const int wr = w / WN, wc = w % WN;
  const int l15 = lane & 15, lhi = lane >> 4;
  const int xmask = (l15 & 7) << 4;            // read-side byte swizzle
  const int smask = ((tid >> 3) & 7) << 3;     // stage-side element swizzle
  int mt, nt_;
  if constexpr (SWZ) {
    int lin = blockIdx.x + blockIdx.y * gridDim.x;
    int nwg = gridDim.x * gridDim.y;
    int cpx = nwg >> 3;
    int s = (lin & 7) * cpx + (lin >> 3);
    int gdy = gridDim.y;
    mt = s / gdy; nt_ = s - mt * gdy;
  } else { mt = blockIdx.x; nt_ = blockIdx.y; }
  const int m0 = mt * BM;
  const int n0 = nt_ * BN;
  const int kbeg = blockIdx.z * Ksub;

  f32x4 acc[MREP][NREP] = {};
  constexpr int AR = ABYTES / 4096;
  constexpr int BR = BBYTES / 4096;
  constexpr int NL = AR + BR;   // gload16 per stage

  auto stage = [&](int buf, int k0) {
    #pragma unroll
    for (int r = 0; r < AR; ++r) {
      int o = r * 4096 + tid * 16;          // byte offset within A buffer
      int row = o >> 7;                     // 128 B per row (64 bf16)
      int kc = (((o & 127) >> 1)) ^ smask;  // inverse-swizzled source column
      const unsigned short* src;
      if constexpr (CONV) {
        int m = m0 + row;
        int bb = m >> 8, pix = m & 255;
        int oh = pix >> 4, ow = pix & 15;
        int r12 = k0 >> 9;
        int icc = (k0 & 511) + kc;
        int r1 = r12 >> 2, r2 = r12 & 3;
        int nn = (oh * 4 + r1) * 64 + ow * 4 + r2;
        src = A + ((size_t)(bb * 4096 + nn)) * 512 + icc;
      } else {
        src = A + (size_t)(m0 + row) * lda + k0 + kc;
      }
      gload16(src, (char*)lds_a + buf * ABYTES + r * 4096 + w * 1024);
    }
    #pragma unroll
    for (int r = 0; r < BR; ++r) {
      int o = r * 4096 + tid * 16;
      int row = o >> 7;
      int kc = (((o & 127) >> 1)) ^ smask;
      const unsigned short* src = Bt + (size_t)(n0 + row) * K + k0 + kc;
      gload16(src, (char*)lds_b + buf * BBYTES + r * 4096 + w * 1024);
    }
  };

  auto waitn = [&]() {
    if constexpr (NL == 4)      asm volatile("s_waitcnt vmcnt(4)" ::: "memory");
    else if constexpr (NL == 6) asm volatile("s_waitcnt vmcnt(6)" ::: "memory");
    else                        asm volatile("s_waitcnt vmcnt(8)" ::: "memory");
  };

  auto compute = [&](int buf) {
    const char* pa = (const char*)lds_a + buf * ABYTES;
    const char* pb = (const char*)lds_b + buf * BBYTES;
    #pragma unroll
    for (int kk = 0; kk < BK; kk += 32) {
      bf16x8 af[MREP], bfr[NREP];
      #pragma unroll
      for (int m = 0; m < MREP; ++m)
        af[m] = *(const bf16x8*)(pa + (wr * MREP * 16 + m * 16 + l15) * (BK * 2)
                                 + (((kk << 1) + (lhi << 4)) ^ xmask));
      #pragma unroll
      for (int n = 0; n < NREP; ++n)
        bfr[n] = *(const bf16x8*)(pb + (wc * NREP * 16 + n * 16 + l15) * (BK * 2)
                                  + (((kk << 1) + (lhi << 4)) ^ xmask));
      __builtin_amdgcn_s_setprio(1);
      #pragma unroll
      for (int m = 0; m < MREP; ++m)
        #pragma unroll
        for (int n = 0; n < NREP; ++n)
          acc[m][n] = MFMA16(af[m], bfr[n], acc[m][n]);
      __builtin_amdgcn_s_setprio(0);
    }
  };

  const int nsteps = Ksub / BK;
  stage(0, kbeg);
  int buf = 0;
  for (int t = 0; t < nsteps; ++t) {
    if (t + 1 < nsteps) {
      stage(buf ^ 1, kbeg + (t + 1) * BK);
      waitn();                               // stage(t) done; t+1 stays in flight
    } else {
      asm volatile("s_waitcnt vmcnt(0)" ::: "memory");
    }
    __builtin_amdgcn_s_barrier();            // all waves' stage(t) visible
    compute(buf);
    __builtin_amdgcn_s_barrier();            // protect buf before next overwrite
    buf ^= 1;
  }

  #pragma unroll
  for (int m = 0; m < MREP; ++m) {
    #pragma unroll
    for (int n = 0; n < NREP; ++n) {
      #pragma unroll
      for (int r = 0; r < 4; ++r) {
        int gm = m0 + wr * MREP * 16 + m * 16 + lhi * 4 + r;
        int gn = n0 + wc * NREP * 16 + n * 16 + l15;
        if constexpr (MODE == 0) {
          float v = acc[m][n][r] + bias[gn];
          ((float*)outp)[(size_t)gm * N + gn] = v;
        } else if constexpr (MODE == 3) {
          ((float*)outp)[((size_t)blockIdx.z * M + gm) * N + gn] = acc[m][n][r];
        } else if constexpr (MODE == 4) {
          float v = (acc[m][n][r] + bias[gn]) * 0.18033688011112042f;  // 0.125*log2(e)
          int b_ = gm >> 12, n_ = gm & 4095;
          int hh = gn >> 6, d = gn & 63;
          int qt = n_ >> 4, half = d >> 5, dd = d & 31;
          int ln = (n_ & 15) | ((dd >> 3) << 4);
          ((unsigned short*)outp)[(size_t)(b_ * 8 + hh) * 262144 +
              (qt * 2 + half) * 512 + ln * 8 + (d & 7)] = f2bf(v);
        } else {  // MODE 2: K/V scatter
          float v = acc[m][n][r] + bias[gn];
          unsigned short bv = f2bf(v);
          int bb = gm >> 8, nr = gm & 255;
          if (gn < 512) {
            int hh = gn >> 6, d = gn & 63;
            int t_ = nr >> 4, half = d >> 5, dd = d & 31;
            int ln = (nr & 15) | ((dd >> 3) << 4);
            out_k[(size_t)(bb * 8 + hh) * 16384 +
                  (t_ * 2 + half) * 512 + ln * 8 + (d & 7)] = bv;
          } else {
            int c = gn - 512;
            int hh = c >> 6, d = c & 63;
            int nn = d >> 4, cl = d & 15;
            int ks = nr >> 5, lh = (nr >> 3) & 3;
            out_v[(size_t)(bb * 8 + hh) * 16384 +
                  (nn * 8 + ks) * 512 + (cl | (lh << 4)) * 8 + (nr & 7)] = bv;
          }
        }
      }
    }
  }
}

// ---------------- LayerNorm + split-K(4) reduction + bias ----------------
__global__ __launch_bounds__(64) void ln_kernel(
    const float* __restrict__ part, const float* __restrict__ bsr,
    const float* __restrict__ gamma, const float* __restrict__ beta,
    unsigned short* __restrict__ xln) {
  const int row = blockIdx.x, lane = threadIdx.x;
  float vv[8];
  #pragma unroll
  for (int j = 0; j < 8; ++j) vv[j] = bsr[lane * 8 + j];
  #pragma unroll
  for (int p = 0; p < 4; ++p) {
    const float* pp = part + ((size_t)p * 2048 + row) * 512 + lane * 8;
    float4 a0 = *(const float4*)pp;
    float4 a1 = *(const float4*)(pp + 4);
    vv[0] += a0.x; vv[1] += a0.y; vv[2] += a0.z; vv[3] += a0.w;
    vv[4] += a1.x; vv[5] += a1.y; vv[6] += a1.z; vv[7] += a1.w;
  }
  float s = 0.f, s2 = 0.f;
  #pragma unroll
  for (int j = 0; j < 8; ++j) { s += vv[j]; s2 += vv[j] * vv[j]; }
  #pragma unroll
  for (int m_ = 1; m_ < 64; m_ <<= 1) { s += __shfl_xor(s, m_); s2 += __shfl_xor(s2, m_); }
  float mean = s * (1.f / 512.f);
  float var = s2 * (1.f / 512.f) - mean * mean;
  float inv = rsqrtf(var + 1e-5f);
  #pragma unroll
  for (int j = 0; j < 8; ++j) {
    int c = lane * 8 + j;
    xln[(size_t)row * 512 + c] = f2bf((vv[j] - mean) * inv * gamma[c] + beta[c]);
  }
}

// ---------------- fused attention: block = (b, h, 128 queries), 8 waves ----------------
__global__ __launch_bounds__(512, 4) void attn_kernel(
    const unsigned short* __restrict__ qfrag, const unsigned short* __restrict__ kfrag,
    const unsigned short* __restrict__ vfrag, unsigned short* __restrict__ aout) {
  __shared__ unsigned short k_lds[16384];   // [t(16)][half(2)][lane(64)][8]
  __shared__ unsigned short v_lds[16384];   // [n(4)][ks(8)][lane(64)][8]
  const int tid = threadIdx.x, lane = tid & 63, w = tid >> 6;
  const int l15 = lane & 15;
  const int b = blockIdx.z, h = blockIdx.y;
  const int bh = b * 8 + h;
  const char* kb_ = (const char*)(kfrag + (size_t)bh * 16384);
  const char* vb_ = (const char*)(vfrag + (size_t)bh * 16384);
  #pragma unroll
  for (int r = 0; r < 4; ++r) {
    gload16(kb_ + r * 8192 + tid * 16, (char*)k_lds + r * 8192 + w * 1024);
    gload16(vb_ + r * 8192 + tid * 16, (char*)v_lds + r * 8192 + w * 1024);
  }
  const int qt = blockIdx.x * 8 + w;
  const unsigned short* qbase = qfrag + (size_t)bh * 262144 + (size_t)qt * 1024;
  bf16x8 qf0 = *(const bf16x8*)(qbase + lane * 8);
  bf16x8 qf1 = *(const bf16x8*)(qbase + 512 + lane * 8);
  __syncthreads();

  // swapped QK^T: st[t] holds S2[k = t*16 + lhi*4 + r][q = l15]  (log2-domain)
  f32x4 st[16];
  #pragma unroll
  for (int t = 0; t < 16; ++t) {
    bf16x8 kf0 = *(const bf16x8*)&k_lds[t * 1024 + lane * 8];
    bf16x8 kf1 = *(const bf16x8*)&k_lds[t * 1024 + 512 + lane * 8];
    f32x4 a = {0.f, 0.f, 0.f, 0.f};
    a = MFMA16(kf0, qf0, a);
    a = MFMA16(kf1, qf1, a);
    st[t] = a;
  }

  // no-max softmax: p = 2^s2 ; sum over k (in-lane 64 + 2 cross-group shfl)
  float sum = 0.f;
  unsigned pk2[16][2];
  #pragma unroll
  for (int t = 0; t < 16; ++t) {
    float p0 = fast_exp2(st[t][0]), p1 = fast_exp2(st[t][1]);
    float p2 = fast_exp2(st[t][2]), p3 = fast_exp2(st[t][3]);
    sum += (p0 + p1) + (p2 + p3);
    unsigned r0, r1;
    asm("v_cvt_pk_bf16_f32 %0, %1, %2" : "=v"(r0) : "v"(p0), "v"(p1));
    asm("v_cvt_pk_bf16_f32 %0, %1, %2" : "=v"(r1) : "v"(p2), "v"(p3));
    pk2[t][0] = r0; pk2[t][1] = r1;
  }
  sum += __shfl_xor(sum, 16);
  sum += __shfl_xor(sum, 32);
  float invs = 1.f / sum;   // for q = l15 (lane-local for swapped-PV output)

  // redistribute P into A/B-fragment layout (verified shfl path);
  // PV as mfma(V, P) -> O[d][q=l15]
  const int lhi_ = lane >> 4;
  const int srcA = l15 + (((2 * lhi_) & 3) << 4);
  const int srcB = l15 + (((2 * lhi_ + 1) & 3) << 4);
  const bool hi2 = lhi_ >= 2;
  f32x4 o[4] = {};
  #pragma unroll
  for (int ks = 0; ks < 8; ++ks) {
    union { unsigned u[4]; bf16x8 v; } pu;
    unsigned A0 = __shfl(pk2[2 * ks][0], srcA),     A0b = __shfl(pk2[2 * ks][1], srcA);
    unsigned A1 = __shfl(pk2[2 * ks + 1][0], srcA), A1b = __shfl(pk2[2 * ks + 1][1], srcA);
    unsigned B0 = __shfl(pk2[2 * ks][0], srcB),     B0b = __shfl(pk2[2 * ks][1], srcB);
    unsigned B1 = __shfl(pk2[2 * ks + 1][0], srcB), B1b = __shfl(pk2[2 * ks + 1][1], srcB);
    pu.u[0] = hi2 ? A1 : A0;  pu.u[1] = hi2 ? A1b : A0b;
    pu.u[2] = hi2 ? B1 : B0;  pu.u[3] = hi2 ? B1b : B0b;
    #pragma unroll
    for (int n = 0; n < 4; ++n) {
      bf16x8 vf = *(const bf16x8*)&v_lds[(n * 8 + ks) * 512 + lane * 8];
      o[n] = MFMA16(vf, pu.v, o[n]);   // A=V (row=d), B=P (col=q) -> O[d][q]
    }
  }

  const int q0 = blockIdx.x * 128;
  const int lhi = lane >> 4;
  #pragma unroll
  for (int n = 0; n < 4; ++n) {
    float a0 = o[n][0] * invs, a1 = o[n][1] * invs;
    float a2 = o[n][2] * invs, a3 = o[n][3] * invs;
    unsigned w0, w1;
    asm("v_cvt_pk_bf16_f32 %0, %1, %2" : "=v"(w0) : "v"(a0), "v"(a1));
    asm("v_cvt_pk_bf16_f32 %0, %1, %2" : "=v"(w1) : "v"(a2), "v"(a3));
    u32x2 pr; pr[0] = w0; pr[1] = w1;
    size_t base = (size_t)(b * 4096 + q0 + w * 16 + l15) * 512 + h * 64 + n * 16 + lhi * 4;
    *(u32x2*)(aout + base) = pr;
  }
}

// ---------------- launch ----------------
extern "C" void kernel_launch(void* const* d_in, const int* in_sizes, int n_in,
                              void* d_out, int out_size, void* d_ws, size_t ws_size,
                              hipStream_t stream) {
  const float* x     = (const float*)d_in[0];
  const float* Wq    = (const float*)d_in[1];
  const float* bq    = (const float*)d_in[2];
  const float* Wkv   = (const float*)d_in[3];
  const float* bkv   = (const float*)d_in[4];
  const float* Wp    = (const float*)d_in[5];
  const float* bp    = (const float*)d_in[6];
  const float* Wsr   = (const float*)d_in[7];
  const float* bsr   = (const float*)d_in[8];
  const float* gamma = (const float*)d_in[9];
  const float* beta  = (const float*)d_in[10];

  char* ws = (char*)d_ws;
  unsigned short* xb    = (unsigned short*)(ws + 0);          // 32 MB (later: aout)
  float*          part  = (float*)(ws + 33554432);            // 16 MB (later: qfrag)
  unsigned short* qfrag = (unsigned short*)(ws + 33554432);
  unsigned short* wqt   = (unsigned short*)(ws + 67108864);   // 512 KB
  unsigned short* wkvt  = (unsigned short*)(ws + 67633152);   // 1 MB
  unsigned short* wpt   = (unsigned short*)(ws + 68681728);   // 512 KB
  unsigned short* wsrt  = (unsigned short*)(ws + 69206016);   // 8 MB
  unsigned short* xln   = (unsigned short*)(ws + 77594624);   // 2 MB
  unsigned short* kfrag = (unsigned short*)(ws + 79691776);   // 2 MB
  unsigned short* vfrag = (unsigned short*)(ws + 81788928);   // 2 MB
  unsigned short* aout  = xb;

  pack_x_kernel<<<16384, 256, 0, stream>>>(x, xb);
  pack_w_kernel<<<20480, 256, 0, stream>>>(Wq, Wkv, Wp, Wsr, wqt, wkvt, wpt, wsrt);
  // SR conv as gathered GEMM, split-K=4 -> fp32 partials
  gemm_bf16<2, 2, 2, 2, 3, true, false><<<dim3(32, 8, 4), 256, 0, stream>>>(
      xb, wsrt, nullptr, part, nullptr, nullptr, 2048, 512, 8192, 512, 2048);
  // LN fused with split-K reduce + conv bias
  ln_kernel<<<2048, 64, 0, stream>>>(part, bsr, gamma, beta, xln);
  // KV projection (64x128 tile -> 256 blocks), fragment-layout scatter
  gemm_bf16<2, 2, 2, 4, 2, false, false><<<dim3(32, 8, 1), 256, 0, stream>>>(
      xln, wkvt, bkv, nullptr, kfrag, vfrag, 2048, 1024, 512, 512, 512);
  // Q projection (scaled by 0.125*log2e, fragment layout); overwrites `part`
  gemm_bf16<2, 2, 4, 4, 4, false, true><<<dim3(256, 4, 1), 256, 0, stream>>>(
      xb, wqt, bq, qfrag, nullptr, nullptr, 32768, 512, 512, 512, 512);
  attn_kernel<<<dim3(32, 8, 8), 512, 0, stream>>>(qfrag, kfrag, vfrag, aout);
  // output projection, XCD-swizzled
  gemm_bf16<2, 2, 4, 4, 0, false, true><<<dim3(256, 4, 1), 256, 0, stream>>>(
      aout, wpt, bp, (float*)d_out, nullptr, nullptr, 32768, 512, 512, 512, 512);
}

// Round 8
// 154.261 us; speedup vs baseline: 2.0030x; 1.0937x over previous
//
#include <hip/hip_runtime.h>
#include <stdint.h>

typedef __attribute__((ext_vector_type(8))) short bf16x8;
typedef __attribute__((ext_vector_type(4))) float f32x4;
typedef __attribute__((ext_vector_type(2))) unsigned u32x2;

#define MFMA16(a,b,c) __builtin_amdgcn_mfma_f32_16x16x32_bf16(a,b,c,0,0,0)

typedef const __attribute__((address_space(1))) void GV;
typedef __attribute__((address_space(3))) void LV;

static __device__ __forceinline__ void gload16(const void* g, void* l) {
  __builtin_amdgcn_global_load_lds((GV*)g, (LV*)l, 16, 0, 0);
}

static __device__ __forceinline__ unsigned short f2bf(float f) {
  union { float f; unsigned u; } x; x.f = f;
  unsigned r = x.u + 0x7FFFu + ((x.u >> 16) & 1u);
  return (unsigned short)(r >> 16);
}

static __device__ __forceinline__ float fast_exp2(float x) {
#if __has_builtin(__builtin_amdgcn_exp2f)
  return __builtin_amdgcn_exp2f(x);
#else
  return __expf(x * 0.6931471805599453f);
#endif
}

// ---------------- pack: x -> bf16, weights -> transposed bf16 (all coalesced) ----------------
__global__ __launch_bounds__(256) void pack_all(
    const float* __restrict__ x, const float* __restrict__ Wq,
    const float* __restrict__ Wkv, const float* __restrict__ Wp,
    const float* __restrict__ Wsr,
    unsigned short* __restrict__ xb, unsigned short* __restrict__ wqt,
    unsigned short* __restrict__ wkvt, unsigned short* __restrict__ wpt,
    unsigned short* __restrict__ wsrt) {
  const int tid = threadIdx.x;
  int bid = blockIdx.x;
  if (bid < 16384) {                      // x -> bf16, 4 floats/thread
    int i = bid * 256 + tid;
    float4 v = ((const float4*)x)[i];
    unsigned a0 = f2bf(v.x), a1 = f2bf(v.y), a2 = f2bf(v.z), a3 = f2bf(v.w);
    uint2 pk; pk.x = a0 | (a1 << 16); pk.y = a2 | (a3 << 16);
    ((uint2*)xb)[i] = pk;
    return;
  }
  bid -= 16384;
  __shared__ float lsm[8704];             // 64x65 tiles / 512x17 for Wsr

  auto wtile = [&](const float* __restrict__ W, unsigned short* __restrict__ out,
                   int ldw, int tr, int tc) {
    int k0 = tr * 64, n0 = tc * 64;
    #pragma unroll
    for (int i = 0; i < 16; ++i) {
      int idx = i * 256 + tid; int r = idx >> 6, c = idx & 63;
      lsm[r * 65 + c] = W[(size_t)(k0 + r) * ldw + n0 + c];
    }
    __syncthreads();
    #pragma unroll
    for (int i = 0; i < 16; ++i) {
      int idx = i * 256 + tid; int n = idx >> 6, k = idx & 63;
      out[(size_t)(n0 + n) * 512 + k0 + k] = f2bf(lsm[k * 65 + n]);
    }
  };

  if (bid < 64) { wtile(Wq, wqt, 512, bid >> 3, bid & 7); return; }
  bid -= 64;
  if (bid < 128) { wtile(Wkv, wkvt, 1024, bid >> 4, bid & 15); return; }
  bid -= 128;
  if (bid < 64) { wtile(Wp, wpt, 512, bid >> 3, bid & 7); return; }
  bid -= 64;
  // Wsr: per oc, transpose [ic(512)][r12(16)] -> wsrt[oc][r12][ic]
  int oc = bid;
  #pragma unroll
  for (int i = 0; i < 32; ++i) {
    int idx = i * 256 + tid;
    lsm[(idx >> 4) * 17 + (idx & 15)] = Wsr[(size_t)oc * 8192 + idx];
  }
  __syncthreads();
  #pragma unroll
  for (int i = 0; i < 32; ++i) {
    int idx = i * 256 + tid;                      // idx = r12*512 + ic
    int ic = idx & 511, r12 = idx >> 9;
    wsrt[(size_t)oc * 8192 + idx] = f2bf(lsm[ic * 17 + r12]);
  }
}

// ---------------- GEMM body: C = A * Bt^T (+bias) ----------------
// Double-buffered LDS + counted vmcnt (T4), XOR swizzle (T2), setprio (T5).
// MODE 0: fp32 row-major out (+bias)
// MODE 2: K/V fragment-layout scatter (+bias)
// MODE 3: conv split-K fp32 partial (no bias)
// MODE 4: Q fragment-layout scatter (+bias, * 0.125*log2e)
template<int WM, int WN, int MREP, int NREP, int MODE, bool CONV>
static __device__ __forceinline__ void gemm_body(
    unsigned short* lds_a, unsigned short* lds_b,
    const unsigned short* __restrict__ A, const unsigned short* __restrict__ Bt,
    const float* __restrict__ bias, void* __restrict__ outp,
    unsigned short* __restrict__ out_k, unsigned short* __restrict__ out_v,
    int M, int N, int K, int lda, int Ksub, int m0, int n0, int kbeg, int zslice) {
  constexpr int BM = WM * MREP * 16;
  constexpr int BN = WN * NREP * 16;
  constexpr int BK = 64;
  constexpr int ABYTES = BM * BK * 2;
  constexpr int BBYTES = BN * BK * 2;
  const int tid = threadIdx.x;
  const int lane = tid & 63, w = tid >> 6;
  const int wr = w / WN, wc = w % WN;
  const int l15 = lane & 15, lhi = lane >> 4;
  const int xmask = (l15 & 7) << 4;            // read-side byte swizzle
  const int smask = ((tid >> 3) & 7) << 3;     // stage-side element swizzle

  f32x4 acc[MREP][NREP] = {};
  constexpr int AR = ABYTES / 4096;
  constexpr int BR = BBYTES / 4096;
  constexpr int NL = AR + BR;

  auto stage = [&](int buf, int k0) {
    #pragma unroll
    for (int r = 0; r < AR; ++r) {
      int o = r * 4096 + tid * 16;
      int row = o >> 7;
      int kc = (((o & 127) >> 1)) ^ smask;
      const unsigned short* src;
      if constexpr (CONV) {
        int m = m0 + row;
        int bb = m >> 8, pix = m & 255;
        int oh = pix >> 4, ow = pix & 15;
        int r12 = k0 >> 9;
        int icc = (k0 & 511) + kc;
        int r1 = r12 >> 2, r2 = r12 & 3;
        int nn = (oh * 4 + r1) * 64 + ow * 4 + r2;
        src = A + ((size_t)(bb * 4096 + nn)) * 512 + icc;
      } else {
        src = A + (size_t)(m0 + row) * lda + k0 + kc;
      }
      gload16(src, (char*)lds_a + buf * ABYTES + r * 4096 + w * 1024);
    }
    #pragma unroll
    for (int r = 0; r < BR; ++r) {
      int o = r * 4096 + tid * 16;
      int row = o >> 7;
      int kc = (((o & 127) >> 1)) ^ smask;
      const unsigned short* src = Bt + (size_t)(n0 + row) * K + k0 + kc;
      gload16(src, (char*)lds_b + buf * BBYTES + r * 4096 + w * 1024);
    }
  };

  auto waitn = [&]() {
    if constexpr (NL == 4)      asm volatile("s_waitcnt vmcnt(4)" ::: "memory");
    else if constexpr (NL == 6) asm volatile("s_waitcnt vmcnt(6)" ::: "memory");
    else                        asm volatile("s_waitcnt vmcnt(8)" ::: "memory");
  };

  auto compute = [&](int buf) {
    const char* pa = (const char*)lds_a + buf * ABYTES;
    const char* pb = (const char*)lds_b + buf * BBYTES;
    #pragma unroll
    for (int kk = 0; kk < BK; kk += 32) {
      bf16x8 af[MREP], bfr[NREP];
      #pragma unroll
      for (int m = 0; m < MREP; ++m)
        af[m] = *(const bf16x8*)(pa + (wr * MREP * 16 + m * 16 + l15) * (BK * 2)
                                 + (((kk << 1) + (lhi << 4)) ^ xmask));
      #pragma unroll
      for (int n = 0; n < NREP; ++n)
        bfr[n] = *(const bf16x8*)(pb + (wc * NREP * 16 + n * 16 + l15) * (BK * 2)
                                  + (((kk << 1) + (lhi << 4)) ^ xmask));
      __builtin_amdgcn_s_setprio(1);
      #pragma unroll
      for (int m = 0; m < MREP; ++m)
        #pragma unroll
        for (int n = 0; n < NREP; ++n)
          acc[m][n] = MFMA16(af[m], bfr[n], acc[m][n]);
      __builtin_amdgcn_s_setprio(0);
    }
  };

  const int nsteps = Ksub / BK;
  stage(0, kbeg);
  int buf = 0;
  for (int t = 0; t < nsteps; ++t) {
    if (t + 1 < nsteps) {
      stage(buf ^ 1, kbeg + (t + 1) * BK);
      waitn();                               // stage(t) done; t+1 stays in flight
    } else {
      asm volatile("s_waitcnt vmcnt(0)" ::: "memory");
    }
    __builtin_amdgcn_s_barrier();            // all waves' stage(t) visible
    compute(buf);
    __builtin_amdgcn_s_barrier();            // protect buf before next overwrite
    buf ^= 1;
  }

  #pragma unroll
  for (int m = 0; m < MREP; ++m) {
    #pragma unroll
    for (int n = 0; n < NREP; ++n) {
      #pragma unroll
      for (int r = 0; r < 4; ++r) {
        int gm = m0 + wr * MREP * 16 + m * 16 + lhi * 4 + r;
        int gn = n0 + wc * NREP * 16 + n * 16 + l15;
        if constexpr (MODE == 0) {
          float v = acc[m][n][r] + bias[gn];
          ((float*)outp)[(size_t)gm * N + gn] = v;
        } else if constexpr (MODE == 3) {
          ((float*)outp)[((size_t)zslice * M + gm) * N + gn] = acc[m][n][r];
        } else if constexpr (MODE == 4) {
          float v = (acc[m][n][r] + bias[gn]) * 0.18033688011112042f;  // 0.125*log2(e)
          int b_ = gm >> 12, n_ = gm & 4095;
          int hh = gn >> 6, d = gn & 63;
          int qt = n_ >> 4, half = d >> 5, dd = d & 31;
          int ln = (n_ & 15) | ((dd >> 3) << 4);
          ((unsigned short*)outp)[(size_t)(b_ * 8 + hh) * 262144 +
              (qt * 2 + half) * 512 + ln * 8 + (d & 7)] = f2bf(v);
        } else {  // MODE 2: K/V scatter
          float v = acc[m][n][r] + bias[gn];
          unsigned short bv = f2bf(v);
          int bb = gm >> 8, nr = gm & 255;
          if (gn < 512) {
            int hh = gn >> 6, d = gn & 63;
            int t_ = nr >> 4, half = d >> 5, dd = d & 31;
            int ln = (nr & 15) | ((dd >> 3) << 4);
            out_k[(size_t)(bb * 8 + hh) * 16384 +
                  (t_ * 2 + half) * 512 + ln * 8 + (d & 7)] = bv;
          } else {
            int c = gn - 512;
            int hh = c >> 6, d = c & 63;
            int nn = d >> 4, cl = d & 15;
            int ks = nr >> 5, lh = (nr >> 3) & 3;
            out_v[(size_t)(bb * 8 + hh) * 16384 +
                  (nn * 8 + ks) * 512 + (cl | (lh << 4)) * 8 + (nr & 7)] = bv;
          }
        }
      }
    }
  }
}

// standalone GEMM kernel (conv, out-proj), 3D grid + optional XCD swizzle
template<int WM, int WN, int MREP, int NREP, int MODE, bool CONV, bool SWZ>
__global__ __launch_bounds__(256) void gemm_bf16(
    const unsigned short* __restrict__ A, const unsigned short* __restrict__ Bt,
    const float* __restrict__ bias, void* __restrict__ outp,
    unsigned short* __restrict__ out_k, unsigned short* __restrict__ out_v,
    int M, int N, int K, int lda, int Ksub) {
  constexpr int BM = WM * MREP * 16;
  constexpr int BN = WN * NREP * 16;
  __shared__ unsigned short lds_a[2 * BM * 64];
  __shared__ unsigned short lds_b[2 * BN * 64];
  int mt, nt_;
  if constexpr (SWZ) {
    int lin = blockIdx.x + blockIdx.y * gridDim.x;
    int nwg = gridDim.x * gridDim.y;
    int cpx = nwg >> 3;
    int s = (lin & 7) * cpx + (lin >> 3);
    int gdy = gridDim.y;
    mt = s / gdy; nt_ = s - mt * gdy;
  } else { mt = blockIdx.x; nt_ = blockIdx.y; }
  gemm_body<WM, WN, MREP, NREP, MODE, CONV>(
      lds_a, lds_b, A, Bt, bias, outp, out_k, out_v,
      M, N, K, lda, Ksub, mt * BM, nt_ * BN, blockIdx.z * Ksub, blockIdx.z);
}

// fused Q-proj (1024 blocks, swizzled) + KV-proj (128 blocks)
__global__ __launch_bounds__(256) void proj_fused(
    const unsigned short* __restrict__ xb, const unsigned short* __restrict__ wqt,
    const float* __restrict__ bq, unsigned short* __restrict__ qfrag,
    const unsigned short* __restrict__ xln, const unsigned short* __restrict__ wkvt,
    const float* __restrict__ bkv, unsigned short* __restrict__ kfrag,
    unsigned short* __restrict__ vfrag) {
  __shared__ unsigned short lds_a[2 * 128 * 64];
  __shared__ unsigned short lds_b[2 * 128 * 64];
  int bx = blockIdx.x;
  if (bx < 1024) {
    int s = (bx & 7) * 128 + (bx >> 3);          // XCD swizzle over 1024
    int mt = s >> 2, nt_ = s & 3;
    gemm_body<2, 2, 4, 4, 4, false>(
        lds_a, lds_b, xb, wqt, bq, qfrag, nullptr, nullptr,
        32768, 512, 512, 512, 512, mt * 128, nt_ * 128, 0, 0);
  } else {
    int b2 = bx - 1024;
    int mt = b2 >> 3, nt_ = b2 & 7;
    gemm_body<2, 2, 4, 4, 2, false>(
        lds_a, lds_b, xln, wkvt, bkv, nullptr, kfrag, vfrag,
        2048, 1024, 512, 512, 512, mt * 128, nt_ * 128, 0, 0);
  }
}

// ---------------- LayerNorm + split-K(8) reduction + bias ----------------
__global__ __launch_bounds__(64) void ln_kernel(
    const float* __restrict__ part, const float* __restrict__ bsr,
    const float* __restrict__ gamma, const float* __restrict__ beta,
    unsigned short* __restrict__ xln) {
  const int row = blockIdx.x, lane = threadIdx.x;
  float vv[8];
  #pragma unroll
  for (int j = 0; j < 8; ++j) vv[j] = bsr[lane * 8 + j];
  #pragma unroll
  for (int p = 0; p < 8; ++p) {
    const float* pp = part + ((size_t)p * 2048 + row) * 512 + lane * 8;
    float4 a0 = *(const float4*)pp;
    float4 a1 = *(const float4*)(pp + 4);
    vv[0] += a0.x; vv[1] += a0.y; vv[2] += a0.z; vv[3] += a0.w;
    vv[4] += a1.x; vv[5] += a1.y; vv[6] += a1.z; vv[7] += a1.w;
  }
  float s = 0.f, s2 = 0.f;
  #pragma unroll
  for (int j = 0; j < 8; ++j) { s += vv[j]; s2 += vv[j] * vv[j]; }
  #pragma unroll
  for (int m_ = 1; m_ < 64; m_ <<= 1) { s += __shfl_xor(s, m_); s2 += __shfl_xor(s2, m_); }
  float mean = s * (1.f / 512.f);
  float var = s2 * (1.f / 512.f) - mean * mean;
  float inv = rsqrtf(var + 1e-5f);
  #pragma unroll
  for (int j = 0; j < 8; ++j) {
    int c = lane * 8 + j;
    xln[(size_t)row * 512 + c] = f2bf((vv[j] - mean) * inv * gamma[c] + beta[c]);
  }
}

// ---------------- fused attention: block = (b, h, 128 queries), 8 waves ----------------
__global__ __launch_bounds__(512, 4) void attn_kernel(
    const unsigned short* __restrict__ qfrag, const unsigned short* __restrict__ kfrag,
    const unsigned short* __restrict__ vfrag, unsigned short* __restrict__ aout) {
  __shared__ unsigned short k_lds[16384];   // [t(16)][half(2)][lane(64)][8]
  __shared__ unsigned short v_lds[16384];   // [n(4)][ks(8)][lane(64)][8]
  const int tid = threadIdx.x, lane = tid & 63, w = tid >> 6;
  const int l15 = lane & 15;
  const int b = blockIdx.z, h = blockIdx.y;
  const int bh = b * 8 + h;
  const char* kb_ = (const char*)(kfrag + (size_t)bh * 16384);
  const char* vb_ = (const char*)(vfrag + (size_t)bh * 16384);
  #pragma unroll
  for (int r = 0; r < 4; ++r) {
    gload16(kb_ + r * 8192 + tid * 16, (char*)k_lds + r * 8192 + w * 1024);
    gload16(vb_ + r * 8192 + tid * 16, (char*)v_lds + r * 8192 + w * 1024);
  }
  const int qt = blockIdx.x * 8 + w;
  const unsigned short* qbase = qfrag + (size_t)bh * 262144 + (size_t)qt * 1024;
  bf16x8 qf0 = *(const bf16x8*)(qbase + lane * 8);
  bf16x8 qf1 = *(const bf16x8*)(qbase + 512 + lane * 8);
  __syncthreads();

  // swapped QK^T: st[t] holds S2[k = t*16 + lhi*4 + r][q = l15]  (log2-domain)
  f32x4 st[16];
  #pragma unroll
  for (int t = 0; t < 16; ++t) {
    bf16x8 kf0 = *(const bf16x8*)&k_lds[t * 1024 + lane * 8];
    bf16x8 kf1 = *(const bf16x8*)&k_lds[t * 1024 + 512 + lane * 8];
    f32x4 a = {0.f, 0.f, 0.f, 0.f};
    a = MFMA16(kf0, qf0, a);
    a = MFMA16(kf1, qf1, a);
    st[t] = a;
  }

  // no-max softmax: p = 2^s2 ; sum over k (in-lane 64 + 2 cross-group shfl)
  float sum = 0.f;
  unsigned pk2[16][2];
  #pragma unroll
  for (int t = 0; t < 16; ++t) {
    float p0 = fast_exp2(st[t][0]), p1 = fast_exp2(st[t][1]);
    float p2 = fast_exp2(st[t][2]), p3 = fast_exp2(st[t][3]);
    sum += (p0 + p1) + (p2 + p3);
    unsigned r0, r1;
    asm("v_cvt_pk_bf16_f32 %0, %1, %2" : "=v"(r0) : "v"(p0), "v"(p1));
    asm("v_cvt_pk_bf16_f32 %0, %1, %2" : "=v"(r1) : "v"(p2), "v"(p3));
    pk2[t][0] = r0; pk2[t][1] = r1;
  }
  sum += __shfl_xor(sum, 16);
  sum += __shfl_xor(sum, 32);
  float invs = 1.f / sum;   // for q = l15 (lane-local for swapped-PV output)

  // redistribute P into A/B-fragment layout (verified shfl path);
  // PV as mfma(V, P) -> O[d][q=l15]
  const int lhi_ = lane >> 4;
  const int srcA = l15 + (((2 * lhi_) & 3) << 4);
  const int srcB = l15 + (((2 * lhi_ + 1) & 3) << 4);
  const bool hi2 = lhi_ >= 2;
  f32x4 o[4] = {};
  #pragma unroll
  for (int ks = 0; ks < 8; ++ks) {
    union { unsigned u[4]; bf16x8 v; } pu;
    unsigned A0 = __shfl(pk2[2 * ks][0], srcA),     A0b = __shfl(pk2[2 * ks][1], srcA);
    unsigned A1 = __shfl(pk2[2 * ks + 1][0], srcA), A1b = __shfl(pk2[2 * ks + 1][1], srcA);
    unsigned B0 = __shfl(pk2[2 * ks][0], srcB),     B0b = __shfl(pk2[2 * ks][1], srcB);
    unsigned B1 = __shfl(pk2[2 * ks + 1][0], srcB), B1b = __shfl(pk2[2 * ks + 1][1], srcB);
    pu.u[0] = hi2 ? A1 : A0;  pu.u[1] = hi2 ? A1b : A0b;
    pu.u[2] = hi2 ? B1 : B0;  pu.u[3] = hi2 ? B1b : B0b;
    #pragma unroll
    for (int n = 0; n < 4; ++n) {
      bf16x8 vf = *(const bf16x8*)&v_lds[(n * 8 + ks) * 512 + lane * 8];
      o[n] = MFMA16(vf, pu.v, o[n]);   // A=V (row=d), B=P (col=q) -> O[d][q]
    }
  }

  const int q0 = blockIdx.x * 128;
  const int lhi = lane >> 4;
  #pragma unroll
  for (int n = 0; n < 4; ++n) {
    float a0 = o[n][0] * invs, a1 = o[n][1] * invs;
    float a2 = o[n][2] * invs, a3 = o[n][3] * invs;
    unsigned w0, w1;
    asm("v_cvt_pk_bf16_f32 %0, %1, %2" : "=v"(w0) : "v"(a0), "v"(a1));
    asm("v_cvt_pk_bf16_f32 %0, %1, %2" : "=v"(w1) : "v"(a2), "v"(a3));
    u32x2 pr; pr[0] = w0; pr[1] = w1;
    size_t base = (size_t)(b * 4096 + q0 + w * 16 + l15) * 512 + h * 64 + n * 16 + lhi * 4;
    *(u32x2*)(aout + base) = pr;
  }
}

// ---------------- launch ----------------
extern "C" void kernel_launch(void* const* d_in, const int* in_sizes, int n_in,
                              void* d_out, int out_size, void* d_ws, size_t ws_size,
                              hipStream_t stream) {
  const float* x     = (const float*)d_in[0];
  const float* Wq    = (const float*)d_in[1];
  const float* bq    = (const float*)d_in[2];
  const float* Wkv   = (const float*)d_in[3];
  const float* bkv   = (const float*)d_in[4];
  const float* Wp    = (const float*)d_in[5];
  const float* bp    = (const float*)d_in[6];
  const float* Wsr   = (const float*)d_in[7];
  const float* bsr   = (const float*)d_in[8];
  const float* gamma = (const float*)d_in[9];
  const float* beta  = (const float*)d_in[10];

  char* ws = (char*)d_ws;
  unsigned short* xb    = (unsigned short*)(ws + 0);          // 32 MB (later: aout)
  float*          part  = (float*)(ws + 33554432);            // 32 MB (later: qfrag)
  unsigned short* qfrag = (unsigned short*)(ws + 33554432);
  unsigned short* wqt   = (unsigned short*)(ws + 67108864);   // 512 KB
  unsigned short* wkvt  = (unsigned short*)(ws + 67633152);   // 1 MB
  unsigned short* wpt   = (unsigned short*)(ws + 68681728);   // 512 KB
  unsigned short* wsrt  = (unsigned short*)(ws + 69206016);   // 8 MB
  unsigned short* xln   = (unsigned short*)(ws + 77594624);   // 2 MB
  unsigned short* kfrag = (unsigned short*)(ws + 79691776);   // 2 MB
  unsigned short* vfrag = (unsigned short*)(ws + 81788928);   // 2 MB
  unsigned short* aout  = xb;

  // pack x + all weight transposes (coalesced via LDS tiles), one dispatch
  pack_all<<<17152, 256, 0, stream>>>(x, Wq, Wkv, Wp, Wsr, xb, wqt, wkvt, wpt, wsrt);
  // SR conv as gathered GEMM, 128x128 tile, split-K=8 -> fp32 partials
  gemm_bf16<2, 2, 4, 4, 3, true, true><<<dim3(16, 4, 8), 256, 0, stream>>>(
      xb, wsrt, nullptr, part, nullptr, nullptr, 2048, 512, 8192, 512, 1024);
  // LN fused with split-K reduce + conv bias
  ln_kernel<<<2048, 64, 0, stream>>>(part, bsr, gamma, beta, xln);
  // fused Q-proj + KV-proj (Q scaled by 0.125*log2e; both fragment-layout)
  proj_fused<<<1152, 256, 0, stream>>>(xb, wqt, bq, qfrag, xln, wkvt, bkv, kfrag, vfrag);
  attn_kernel<<<dim3(32, 8, 8), 512, 0, stream>>>(qfrag, kfrag, vfrag, aout);
  // output projection, XCD-swizzled
  gemm_bf16<2, 2, 4, 4, 0, false, true><<<dim3(256, 4, 1), 256, 0, stream>>>(
      aout, wpt, bp, (float*)d_out, nullptr, nullptr, 32768, 512, 512, 512, 512);
}